// Round 17
// baseline (154.044 us; speedup 1.0000x reference)
//
#include <hip/hip_runtime.h>

// deformMP: B=4, Cc=256, ci=64, H=W=128, GN groups=32, eps=1e-5
// ws: xdTbf[2.10M fl-equiv NHWC bf16] t3bf[8.39M] mrs1/2 wA1f wBf wofBf w3Bf ps ps2
// k_mega v5: deform path is register-direct (gather -> A-frag in regs -> MFMA),
// no LDS round-trip, no barriers between offsL and A2. Off-conv im2col unchanged.

#define HW 16384
#define WIDTH 128

typedef __attribute__((ext_vector_type(8))) short bf16x8;
typedef __attribute__((ext_vector_type(4))) float f32x4;

__device__ __forceinline__ unsigned short f2bf(float f) {
  unsigned int u = __float_as_uint(f);
  u = (u + 0x7fffu + ((u >> 16) & 1u)) >> 16;  // RNE
  return (unsigned short)u;
}
__device__ __forceinline__ float bflo(unsigned int u) { return __uint_as_float(u << 16); }
__device__ __forceinline__ float bfhi(unsigned int u) { return __uint_as_float(u & 0xffff0000u); }

// ---- K0: weight repack (unchanged) ----
__global__ __launch_bounds__(256) void k_prep(const float* __restrict__ w1, const float* __restrict__ w3,
                                              const float* __restrict__ wdef, const float* __restrict__ woff,
                                              unsigned short* __restrict__ wA1f,
                                              unsigned short* __restrict__ wBf,
                                              unsigned short* __restrict__ wofBf,
                                              unsigned short* __restrict__ w3Bf) {
  int i = blockIdx.x * 256 + threadIdx.x;
  if (i < 16384) {
    int j = i & 7;
    int lane = (i >> 3) & 63;
    int m = (i >> 9) & 3;
    int kt = i >> 11;
    int o = (m << 4) + (lane & 15);
    int c = kt * 32 + ((lane >> 4) << 3) + j;
    wA1f[i] = f2bf(w1[(size_t)o * 256 + c]);
  }
  if (i < 36864) {
    int j = i & 7;
    int lane = (i >> 3) & 63;
    int n = (i >> 9) & 3;
    int kt = i >> 11;
    int kk = kt * 32 + ((lane >> 4) << 3) + j;
    int tap = kk >> 6, c = kk & 63;
    int o = (n << 4) + (lane & 15);
    wBf[i] = f2bf(wdef[(size_t)o * 576 + c * 9 + tap]);
  }
  if (i < 18432) {
    int j = i & 7;
    int lane = (i >> 3) & 63;
    int n = (i >> 9) & 1;
    int kt = i >> 10;
    int kk = kt * 32 + ((lane >> 4) << 3) + j;
    int tap = kk >> 6, c = kk & 63;
    int o = (n << 4) + (lane & 15);
    wofBf[i] = (o < 18) ? f2bf(woff[((size_t)(o * 64 + c)) * 9 + tap]) : (unsigned short)0;
  }
  if (i < 32768) {
    int j = i & 7;
    int lane = (i >> 3) & 63;
    int n = (i >> 9) & 15;
    int kt = i >> 13;
    int c = kt * 32 + ((lane >> 4) << 3) + j;
    int o = (n << 4) + (lane & 15);
    w3Bf[i] = f2bf(w3[(size_t)o * 64 + c]);
  }
}

// ---- K1: conv1x1 256->64 via bf16 MFMA, double-buffered staging, bf16 NHWC + GN1 partials ----
__global__ __launch_bounds__(256) void k_conv1m(const float* __restrict__ x,
                                                const unsigned short* __restrict__ wA1f,
                                                unsigned short* __restrict__ xdT, float* __restrict__ ps) {
  __shared__ unsigned short xs[2][64][72];
  __shared__ float lds_s[4][32], lds_ss[4][32];
  int tid = threadIdx.x;
  int wave = tid >> 6, lane = tid & 63;
  int b = blockIdx.x >> 8;
  int chunk = blockIdx.x & 255;
  int px0 = chunk << 6;
  int pxl = lane & 15, q = lane >> 4;
  const float* xb = x + (size_t)b * 256 * HW + px0;
  const bf16x8* wAp = (const bf16x8*)wA1f;
  int sc = tid >> 4;
  int sq = tid & 15;
  f32x4 acc[4];
#pragma unroll
  for (int m = 0; m < 4; m++) acc[m] = (f32x4){0.f, 0.f, 0.f, 0.f};

  float4 vr[4];
#pragma unroll
  for (int r = 0; r < 4; r++)
    vr[r] = *(const float4*)(xb + (size_t)(r * 16 + sc) * HW + sq * 4);
#pragma unroll
  for (int r = 0; r < 4; r++) {
    int c = r * 16 + sc;
    xs[0][sq * 4 + 0][c] = f2bf(vr[r].x);
    xs[0][sq * 4 + 1][c] = f2bf(vr[r].y);
    xs[0][sq * 4 + 2][c] = f2bf(vr[r].z);
    xs[0][sq * 4 + 3][c] = f2bf(vr[r].w);
  }
  __syncthreads();

  for (int cb = 0; cb < 4; cb++) {
    int cur = cb & 1;
    if (cb < 3) {
#pragma unroll
      for (int r = 0; r < 4; r++)
        vr[r] = *(const float4*)(xb + (size_t)((cb + 1) * 64 + r * 16 + sc) * HW + sq * 4);
    }
#pragma unroll
    for (int kt = 0; kt < 2; kt++) {
      bf16x8 bfrag = *(const bf16x8*)&xs[cur][wave * 16 + pxl][kt * 32 + q * 8];
      int ktG = cb * 2 + kt;
#pragma unroll
      for (int m = 0; m < 4; m++) {
        bf16x8 af = wAp[(ktG * 4 + m) * 64 + lane];
        acc[m] = __builtin_amdgcn_mfma_f32_16x16x32_bf16(af, bfrag, acc[m], 0, 0, 0);
      }
    }
    if (cb < 3) {
#pragma unroll
      for (int r = 0; r < 4; r++) {
        int c = r * 16 + sc;
        xs[cur ^ 1][sq * 4 + 0][c] = f2bf(vr[r].x);
        xs[cur ^ 1][sq * 4 + 1][c] = f2bf(vr[r].y);
        xs[cur ^ 1][sq * 4 + 2][c] = f2bf(vr[r].z);
        xs[cur ^ 1][sq * 4 + 3][c] = f2bf(vr[r].w);
      }
    }
    __syncthreads();
  }
  unsigned short* xo = xdT + ((size_t)b * HW + px0 + wave * 16 + pxl) * 64 + (q << 2);
#pragma unroll
  for (int m = 0; m < 4; m++) {
    unsigned int u0, u1;
    asm("v_cvt_pk_bf16_f32 %0, %1, %2" : "=v"(u0) : "v"(acc[m][0]), "v"(acc[m][1]));
    asm("v_cvt_pk_bf16_f32 %0, %1, %2" : "=v"(u1) : "v"(acc[m][2]), "v"(acc[m][3]));
    *(uint2*)(xo + m * 16) = make_uint2(u0, u1);
  }
  float s[8], sq2[8];
#pragma unroll
  for (int m = 0; m < 4; m++)
#pragma unroll
    for (int h = 0; h < 2; h++) {
      float a = acc[m][2 * h] + acc[m][2 * h + 1];
      float qq = acc[m][2 * h] * acc[m][2 * h] + acc[m][2 * h + 1] * acc[m][2 * h + 1];
      s[m * 2 + h] = a; sq2[m * 2 + h] = qq;
    }
#pragma unroll
  for (int i = 0; i < 8; i++) {
#pragma unroll
    for (int off = 8; off; off >>= 1) {
      s[i] += __shfl_down(s[i], off, 16);
      sq2[i] += __shfl_down(sq2[i], off, 16);
    }
  }
  if (pxl == 0) {
#pragma unroll
    for (int i = 0; i < 8; i++) {
      int m = i >> 1, h = i & 1;
      int g = m * 8 + q * 2 + h;
      lds_s[wave][g] = s[i];
      lds_ss[wave][g] = sq2[i];
    }
  }
  __syncthreads();
  if (tid < 32) {
    float S = lds_s[0][tid] + lds_s[1][tid] + lds_s[2][tid] + lds_s[3][tid];
    float SS = lds_ss[0][tid] + lds_ss[1][tid] + lds_ss[2][tid] + lds_ss[3][tid];
    int bg = b * 32 + tid;
    ps[(bg * 256 + chunk) * 2] = S;
    ps[(bg * 256 + chunk) * 2 + 1] = SS;
  }
}

// ---- K2: finalize GN stats, block-parallel ----
__global__ __launch_bounds__(256) void k_gnfin_p(const float* __restrict__ ps, float* __restrict__ mrs,
                                                 int S, float n) {
  int bg = blockIdx.x;
  float s = 0.f, ss = 0.f;
  for (int i = threadIdx.x; i < S; i += 256) { s += ps[(bg * S + i) * 2]; ss += ps[(bg * S + i) * 2 + 1]; }
#pragma unroll
  for (int off = 32; off; off >>= 1) { s += __shfl_down(s, off); ss += __shfl_down(ss, off); }
  __shared__ float ls[4], lss[4];
  int wv = threadIdx.x >> 6;
  if ((threadIdx.x & 63) == 0) { ls[wv] = s; lss[wv] = ss; }
  __syncthreads();
  if (threadIdx.x == 0) {
    float Sa = ls[0] + ls[1] + ls[2] + ls[3];
    float SSa = lss[0] + lss[1] + lss[2] + lss[3];
    float mu = Sa / n;
    float var = SSa / n - mu * mu;
    mrs[bg] = mu;
    mrs[128 + bg] = rsqrtf(var + 1e-5f);
  }
}

// ---- K3: GN1 + ReLU in place on bf16 xdT ----
__global__ __launch_bounds__(256) void k_gnapply_bf(unsigned short* __restrict__ xdT,
                                                    const float* __restrict__ mrs,
                                                    const float* __restrict__ g1, const float* __restrict__ b1) {
  int i = blockIdx.x * 256 + threadIdx.x;
  int b = i >> 17;
  int ck = i & 7;
  int c0 = ck << 3;
  uint4 v = ((const uint4*)xdT)[i];
  float ga[8], be[8];
#pragma unroll
  for (int j = 0; j < 8; j += 2) {
    int g = (c0 + j) >> 1;
    float mu = mrs[b * 32 + g], rs = mrs[128 + b * 32 + g];
    ga[j] = g1[c0 + j] * rs;     be[j] = b1[c0 + j] - mu * ga[j];
    ga[j + 1] = g1[c0 + j + 1] * rs; be[j + 1] = b1[c0 + j + 1] - mu * ga[j + 1];
  }
  float r[8];
  r[0] = fmaxf(bflo(v.x) * ga[0] + be[0], 0.f);
  r[1] = fmaxf(bfhi(v.x) * ga[1] + be[1], 0.f);
  r[2] = fmaxf(bflo(v.y) * ga[2] + be[2], 0.f);
  r[3] = fmaxf(bfhi(v.y) * ga[3] + be[3], 0.f);
  r[4] = fmaxf(bflo(v.z) * ga[4] + be[4], 0.f);
  r[5] = fmaxf(bfhi(v.z) * ga[5] + be[5], 0.f);
  r[6] = fmaxf(bflo(v.w) * ga[6] + be[6], 0.f);
  r[7] = fmaxf(bfhi(v.w) * ga[7] + be[7], 0.f);
  uint4 o;
  asm("v_cvt_pk_bf16_f32 %0, %1, %2" : "=v"(o.x) : "v"(r[0]), "v"(r[1]));
  asm("v_cvt_pk_bf16_f32 %0, %1, %2" : "=v"(o.y) : "v"(r[2]), "v"(r[3]));
  asm("v_cvt_pk_bf16_f32 %0, %1, %2" : "=v"(o.z) : "v"(r[4]), "v"(r[5]));
  asm("v_cvt_pk_bf16_f32 %0, %1, %2" : "=v"(o.w) : "v"(r[6]), "v"(r[7]));
  ((uint4*)xdT)[i] = o;
}

// ---- K5: MEGA v5 — off-conv im2col (LDS) + register-direct deform + conv2 + GN2 ----
__global__ __launch_bounds__(576, 7) void k_mega(const unsigned short* __restrict__ xdT,
                                                 const unsigned short* __restrict__ wofBf,
                                                 const unsigned short* __restrict__ wBf,
                                                 const unsigned short* __restrict__ w3Bf,
                                                 unsigned short* __restrict__ t3,
                                                 float* __restrict__ ps2) {
  __shared__ unsigned short A[36 * 65 * 8];  // 37,440 B
  __shared__ float offsL[64 * 18];           // 4,608 B
  int tid = threadIdx.x;
  int bb = blockIdx.x >> 8;
  int tileid = blockIdx.x & 255;
  int px0 = tileid << 6;
  const unsigned short* xtf = xdT + (size_t)bb * 64 * HW;  // bf16 NHWC (normalized)
  const char* xbt = (const char*)xtf;
  int wave = tid >> 6;  // 0..8 = tap in off-conv build
  int lane = tid & 63;
  int q16 = lane >> 2;  // build: pair-sub
  int ch4 = lane & 3;   // build: 8-ch chunk
  int kcbyte = (wave * 4 + ch4) * 1040;
  int kq = lane >> 4;

  // ---- P0/P1: fixed-tap im2col build + off-GEMM, two channel halves (unchanged) ----
  f32x4 aoff = {0.f, 0.f, 0.f, 0.f};
  {
    int ky = wave / 3 - 1, kx = wave % 3 - 1;
    int n2 = wave & 1;
    int mh1 = wave >> 1;
    int r1 = mh1 * 16 + (lane & 15);
    for (int h = 0; h < 2; ++h) {
      int co = (h << 6) + (ch4 << 4);
#pragma unroll
      for (int g = 0; g < 4; ++g) {
        int src = (g << 4) + q16;
        int px = px0 + src;
        int sy = (px >> 7) + ky;
        int sx = (px & 127) + kx;
        bool valid = ((unsigned)sy < 128u) && ((unsigned)sx < 128u);
        uint4 v = make_uint4(0u, 0u, 0u, 0u);
        if (valid) v = *(const uint4*)(xbt + (((sy << 7) + sx) << 7) + co);
        *(uint4*)((char*)A + kcbyte + src * 16) = v;
      }
      __syncthreads();
      if (wave < 8) {
        const bf16x8* wp = (const bf16x8*)wofBf;
        __builtin_amdgcn_s_setprio(1);
#pragma unroll
        for (int tap = 0; tap < 9; ++tap) {
          bf16x8 bk = wp[((2 * tap + h) * 2 + n2) * 64 + lane];
          bf16x8 a0 = *(const bf16x8*)((const char*)A + ((tap * 4 + kq) * 65 + r1) * 16);
          aoff = __builtin_amdgcn_mfma_f32_16x16x32_bf16(a0, bk, aoff, 0, 0, 0);
        }
        __builtin_amdgcn_s_setprio(0);
      }
      __syncthreads();
    }
    if (wave < 8) {
      int o = n2 * 16 + (lane & 15);
      if (o < 18) {
        int prow = mh1 * 16 + ((lane >> 4) << 2);
#pragma unroll
        for (int r = 0; r < 4; r++) offsL[(prow + r) * 18 + o] = aoff[r];
      }
    }
  }
  __syncthreads();  // offsL ready; A dead until A2

  // ---- Deform, register-direct: wave = (mh 0..3, nh 0..1); lane = (kq, pxl).
  // Per kt: gather A-frag in regs (row=pxl, k=kq*8+j) and 2 MFMA. No LDS, no barriers.
  f32x4 accA = {0.f, 0.f, 0.f, 0.f};
  f32x4 accB = {0.f, 0.f, 0.f, 0.f};
  int pxl = lane & 15;
  int dmh = wave >> 1, dnh = wave & 1;
  if (wave < 8) {
    int rowl = dmh * 16 + pxl;
    int pxg = px0 + rowl;
    int yy = pxg >> 7, xx = pxg & 127;
    const bf16x8* wp = (const bf16x8*)wBf;
#pragma unroll 2
    for (int tap = 0; tap < 9; ++tap) {
      float dy = offsL[rowl * 18 + 2 * tap];
      float dx = offsL[rowl * 18 + 2 * tap + 1];
      float py = (float)(yy + tap / 3 - 1) + dy;
      float pxx = (float)(xx + tap % 3 - 1) + dx;
      float y0f = floorf(py), x0f = floorf(pxx);
      float ay = py - y0f, ax = pxx - x0f;
      int y0 = (int)y0f, x0 = (int)x0f;
      int y1i = y0 + 1, x1i = x0 + 1;
      float by0 = 1.f - ay, bx0 = 1.f - ax;
      bool vy0 = (unsigned)y0 < 128u, vy1 = (unsigned)y1i < 128u;
      bool vx0 = (unsigned)x0 < 128u, vx1 = (unsigned)x1i < 128u;
      float w00 = (vy0 && vx0) ? by0 * bx0 : 0.f;
      float w01 = (vy0 && vx1) ? by0 * ax : 0.f;
      float w10 = (vy1 && vx0) ? ay * bx0 : 0.f;
      float w11 = (vy1 && vx1) ? ay * ax : 0.f;
      int iy0 = min(max(y0, 0), 127), iy1 = min(max(y1i, 0), 127);
      int ix0 = min(max(x0, 0), 127), ix1 = min(max(x1i, 0), 127);
      int a00 = (iy0 * WIDTH + ix0) << 7;
      int a01 = (iy0 * WIDTH + ix1) << 7;
      int a10 = (iy1 * WIDTH + ix0) << 7;
      int a11 = (iy1 * WIDTH + ix1) << 7;
#pragma unroll
      for (int h = 0; h < 2; ++h) {
        int co = (h << 6) + (kq << 4);
        uint4 v0 = *(const uint4*)(xbt + a00 + co);
        uint4 v1 = *(const uint4*)(xbt + a01 + co);
        uint4 v2 = *(const uint4*)(xbt + a10 + co);
        uint4 v3 = *(const uint4*)(xbt + a11 + co);
        float r[8];
        r[0] = w00 * bflo(v0.x) + w01 * bflo(v1.x) + w10 * bflo(v2.x) + w11 * bflo(v3.x);
        r[1] = w00 * bfhi(v0.x) + w01 * bfhi(v1.x) + w10 * bfhi(v2.x) + w11 * bfhi(v3.x);
        r[2] = w00 * bflo(v0.y) + w01 * bflo(v1.y) + w10 * bflo(v2.y) + w11 * bflo(v3.y);
        r[3] = w00 * bfhi(v0.y) + w01 * bfhi(v1.y) + w10 * bfhi(v2.y) + w11 * bfhi(v3.y);
        r[4] = w00 * bflo(v0.z) + w01 * bflo(v1.z) + w10 * bflo(v2.z) + w11 * bflo(v3.z);
        r[5] = w00 * bfhi(v0.z) + w01 * bfhi(v1.z) + w10 * bfhi(v2.z) + w11 * bfhi(v3.z);
        r[6] = w00 * bflo(v0.w) + w01 * bflo(v1.w) + w10 * bflo(v2.w) + w11 * bflo(v3.w);
        r[7] = w00 * bfhi(v0.w) + w01 * bfhi(v1.w) + w10 * bfhi(v2.w) + w11 * bfhi(v3.w);
        bf16x8 af;
        unsigned int u0, u1, u2, u3;
        asm("v_cvt_pk_bf16_f32 %0, %1, %2" : "=v"(u0) : "v"(r[0]), "v"(r[1]));
        asm("v_cvt_pk_bf16_f32 %0, %1, %2" : "=v"(u1) : "v"(r[2]), "v"(r[3]));
        asm("v_cvt_pk_bf16_f32 %0, %1, %2" : "=v"(u2) : "v"(r[4]), "v"(r[5]));
        asm("v_cvt_pk_bf16_f32 %0, %1, %2" : "=v"(u3) : "v"(r[6]), "v"(r[7]));
        ((unsigned int*)&af)[0] = u0;
        ((unsigned int*)&af)[1] = u1;
        ((unsigned int*)&af)[2] = u2;
        ((unsigned int*)&af)[3] = u3;
        int kt = tap * 2 + h;
        bf16x8 bk0 = wp[(kt * 4 + dnh * 2 + 0) * 64 + lane];
        bf16x8 bk1 = wp[(kt * 4 + dnh * 2 + 1) * 64 + lane];
        accA = __builtin_amdgcn_mfma_f32_16x16x32_bf16(af, bk0, accA, 0, 0, 0);
        accB = __builtin_amdgcn_mfma_f32_16x16x32_bf16(af, bk1, accB, 0, 0, 0);
      }
    }
    // residual (bf16 unpack) — D: col(lane&15)=c within 16-tile, row=(kq*4+r)=px
    int c0 = dnh * 32 + pxl;
    int pb = px0 + dmh * 16 + (kq << 2);
#pragma unroll
    for (int r = 0; r < 4; r++) {
      accA[r] += __uint_as_float((unsigned int)xtf[(size_t)(pb + r) * 64 + c0] << 16);
      accB[r] += __uint_as_float((unsigned int)xtf[(size_t)(pb + r) * 64 + c0 + 16] << 16);
    }
    // A2 write (chunk-major [kc=8][row pad65][16B]) into A's head
    int pxr = dmh * 16 + (kq << 2);
    char* bA = (char*)A + (c0 >> 3) * 1040 + (c0 & 7) * 2;
    char* bB = (char*)A + ((c0 + 16) >> 3) * 1040 + ((c0 + 16) & 7) * 2;
#pragma unroll
    for (int r = 0; r < 4; r++) {
      *(unsigned short*)(bA + (size_t)(pxr + r) * 16) = f2bf(accA[r]);
      *(unsigned short*)(bB + (size_t)(pxr + r) * 16) = f2bf(accB[r]);
    }
  }
  __syncthreads();
  if (wave >= 8) return;

  // ---- P6: GEMM2 (M=64, N=256, K=64) + GN2 partials + bf16 t3 (unchanged) ----
  int n1 = wave & 3;
  f32x4 cA[4], cB[4];
#pragma unroll
  for (int ni = 0; ni < 4; ni++) {
    cA[ni] = (f32x4){0.f, 0.f, 0.f, 0.f};
    cB[ni] = (f32x4){0.f, 0.f, 0.f, 0.f};
  }
  {
    int mt0 = (wave >> 2) * 2;
    const bf16x8* wp2 = (const bf16x8*)w3Bf;
    __builtin_amdgcn_s_setprio(1);
#pragma unroll
    for (int kt = 0; kt < 2; kt++) {
      int kc = kt * 4 + kq;
      bf16x8 aA = *(const bf16x8*)((const char*)A + (size_t)(kc * 65 + mt0 * 16 + (lane & 15)) * 16);
      bf16x8 aB = *(const bf16x8*)((const char*)A + (size_t)(kc * 65 + (mt0 + 1) * 16 + (lane & 15)) * 16);
#pragma unroll
      for (int ni = 0; ni < 4; ni++) {
        int ng = n1 * 4 + ni;
        bf16x8 bk = wp2[(kt * 16 + ng) * 64 + lane];
        cA[ni] = __builtin_amdgcn_mfma_f32_16x16x32_bf16(aA, bk, cA[ni], 0, 0, 0);
        cB[ni] = __builtin_amdgcn_mfma_f32_16x16x32_bf16(aB, bk, cB[ni], 0, 0, 0);
      }
    }
    __builtin_amdgcn_s_setprio(0);
  }
#pragma unroll
  for (int ni = 0; ni < 4; ni++) {
    float s = 0.f, qq = 0.f;
#pragma unroll
    for (int r = 0; r < 4; r++) {
      float v0 = cA[ni][r], v1 = cB[ni][r];
      s += v0 + v1; qq += v0 * v0 + v1 * v1;
    }
    s += __shfl_down(s, 32); qq += __shfl_down(qq, 32);
    s += __shfl_down(s, 16); qq += __shfl_down(qq, 16);
    s += __shfl_down(s, 4);  qq += __shfl_down(qq, 4);
    s += __shfl_down(s, 2);  qq += __shfl_down(qq, 2);
    s += __shfl_down(s, 1);  qq += __shfl_down(qq, 1);
    if (lane == 0 || lane == 8) {
      int g = (n1 * 4 + ni) * 2 + (lane >> 3);
      int slot = ((bb * 32 + g) * 256 + tileid) * 2 + (wave >> 2);
      ps2[slot * 2] = s;
      ps2[slot * 2 + 1] = qq;
    }
  }
  unsigned short* tb = t3 + (size_t)bb * 256 * HW + px0;
  int mtq = (wave >> 2) * 32 + ((lane >> 4) << 2);
#pragma unroll
  for (int ni = 0; ni < 4; ni++) {
    int o = (n1 * 4 + ni) * 16 + (lane & 15);
    unsigned short* p0 = tb + (size_t)o * HW + mtq;
    unsigned int u0, u1, u2, u3;
    asm("v_cvt_pk_bf16_f32 %0, %1, %2" : "=v"(u0) : "v"(cA[ni][0]), "v"(cA[ni][1]));
    asm("v_cvt_pk_bf16_f32 %0, %1, %2" : "=v"(u1) : "v"(cA[ni][2]), "v"(cA[ni][3]));
    asm("v_cvt_pk_bf16_f32 %0, %1, %2" : "=v"(u2) : "v"(cB[ni][0]), "v"(cB[ni][1]));
    asm("v_cvt_pk_bf16_f32 %0, %1, %2" : "=v"(u3) : "v"(cB[ni][2]), "v"(cB[ni][3]));
    *(uint2*)p0 = make_uint2(u0, u1);
    *(uint2*)(p0 + 16) = make_uint2(u2, u3);
  }
}

// ---- K8: out = relu(gn2(t3_bf16)) + x ----
__global__ __launch_bounds__(256) void k_final(const unsigned short* __restrict__ t3, const float* __restrict__ x,
                                               const float* __restrict__ mrs, const float* __restrict__ g3,
                                               const float* __restrict__ b3, float* __restrict__ out) {
  int i4 = blockIdx.x * 256 + threadIdx.x;
  int b = i4 >> 20;
  int c = (i4 >> 12) & 255;
  int g = c >> 3;
  float mu = mrs[b * 32 + g], rs = mrs[128 + b * 32 + g];
  float ga = g3[c] * rs, be = b3[c] - mu * ga;
  uint2 tv = ((const uint2*)t3)[i4];
  float t0 = bflo(tv.x);
  float t1 = bfhi(tv.x);
  float t2 = bflo(tv.y);
  float t3v = bfhi(tv.y);
  float4 xv = ((const float4*)x)[i4];
  float4 r;
  r.x = fmaxf(t0 * ga + be, 0.f) + xv.x;
  r.y = fmaxf(t1 * ga + be, 0.f) + xv.y;
  r.z = fmaxf(t2 * ga + be, 0.f) + xv.z;
  r.w = fmaxf(t3v * ga + be, 0.f) + xv.w;
  ((float4*)out)[i4] = r;
}

extern "C" void kernel_launch(void* const* d_in, const int* in_sizes, int n_in,
                              void* d_out, int out_size, void* d_ws, size_t ws_size,
                              hipStream_t stream) {
  const float* x    = (const float*)d_in[0];
  const float* w1   = (const float*)d_in[1];
  const float* g1   = (const float*)d_in[2];
  const float* b1   = (const float*)d_in[3];
  const float* woff = (const float*)d_in[4];
  const float* wdef = (const float*)d_in[5];
  const float* w3   = (const float*)d_in[6];
  const float* g3   = (const float*)d_in[7];
  const float* b3   = (const float*)d_in[8];
  float* ws = (float*)d_ws;

  unsigned short* xdT = (unsigned short*)ws;               // 4,194,304 ush = 2,097,152 fl
  unsigned short* t3  = (unsigned short*)(ws + 2097152);   // 16,777,216 ush = 8,388,608 fl
  float* base = ws + 2097152 + 8388608;
  float* mrs1 = base;                     // 256
  float* mrs2 = mrs1 + 256;               // 256
  unsigned short* wA1f  = (unsigned short*)(mrs2 + 256);                        // 8,192 fl
  unsigned short* wBf   = (unsigned short*)(mrs2 + 256 + 8192);                 // 18,432 fl
  unsigned short* wofBf = (unsigned short*)(mrs2 + 256 + 8192 + 18432);         // 9,216 fl
  unsigned short* w3Bf  = (unsigned short*)(mrs2 + 256 + 8192 + 18432 + 9216);  // 16,384 fl
  float* ps   = mrs2 + 256 + 8192 + 18432 + 9216 + 16384;  // 65,536
  float* ps2  = ps + 65536;               // 131,072
  float* out  = (float*)d_out;

  hipLaunchKernelGGL(k_prep, dim3(144), dim3(256), 0, stream, w1, w3, wdef, woff, wA1f, wBf, wofBf, w3Bf);
  hipLaunchKernelGGL(k_conv1m, dim3(1024), dim3(256), 0, stream, x, wA1f, xdT, ps);
  hipLaunchKernelGGL(k_gnfin_p, dim3(128), dim3(256), 0, stream, ps, mrs1, 256, (float)(2 * HW));
  hipLaunchKernelGGL(k_gnapply_bf, dim3(2048), dim3(256), 0, stream, xdT, mrs1, g1, b1);
  hipLaunchKernelGGL(k_mega, dim3(1024), dim3(576), 0, stream, xdT, wofBf, wBf, w3Bf, t3, ps2);
  hipLaunchKernelGGL(k_gnfin_p, dim3(128), dim3(256), 0, stream, ps2, mrs2, 512, 131072.f);
  hipLaunchKernelGGL(k_final, dim3(16384), dim3(256), 0, stream, t3, x, mrs2, g3, b3, out);
}

// Round 18
// 112.320 us; speedup vs baseline: 1.3715x; 1.3715x over previous
//
#include <hip/hip_runtime.h>

// deformMP: B=4, Cc=256, ci=64, H=W=128, GN groups=32, eps=1e-5
// ws: xdTbf[2.10M fl-equiv NHWC bf16] t3bf[8.39M] mrs1/2 wA1f wBf wofBf w3Bf ps ps2
// k_mega v6 = round-14/16 proven structure, but 8-wave blocks (512 thr) so
// 4 blocks x 8 waves = 32 waves/CU; offsL aliases A (LDS 37.4KB). Tap 8's build
// is spread over waves 0-3 (one px-group each). All GEMM phases use 8 waves.

#define HW 16384
#define WIDTH 128

typedef __attribute__((ext_vector_type(8))) short bf16x8;
typedef __attribute__((ext_vector_type(4))) float f32x4;

__device__ __forceinline__ unsigned short f2bf(float f) {
  unsigned int u = __float_as_uint(f);
  u = (u + 0x7fffu + ((u >> 16) & 1u)) >> 16;  // RNE
  return (unsigned short)u;
}
__device__ __forceinline__ float bflo(unsigned int u) { return __uint_as_float(u << 16); }
__device__ __forceinline__ float bfhi(unsigned int u) { return __uint_as_float(u & 0xffff0000u); }

// ---- K0: weight repack (unchanged) ----
__global__ __launch_bounds__(256) void k_prep(const float* __restrict__ w1, const float* __restrict__ w3,
                                              const float* __restrict__ wdef, const float* __restrict__ woff,
                                              unsigned short* __restrict__ wA1f,
                                              unsigned short* __restrict__ wBf,
                                              unsigned short* __restrict__ wofBf,
                                              unsigned short* __restrict__ w3Bf) {
  int i = blockIdx.x * 256 + threadIdx.x;
  if (i < 16384) {
    int j = i & 7;
    int lane = (i >> 3) & 63;
    int m = (i >> 9) & 3;
    int kt = i >> 11;
    int o = (m << 4) + (lane & 15);
    int c = kt * 32 + ((lane >> 4) << 3) + j;
    wA1f[i] = f2bf(w1[(size_t)o * 256 + c]);
  }
  if (i < 36864) {
    int j = i & 7;
    int lane = (i >> 3) & 63;
    int n = (i >> 9) & 3;
    int kt = i >> 11;
    int kk = kt * 32 + ((lane >> 4) << 3) + j;
    int tap = kk >> 6, c = kk & 63;
    int o = (n << 4) + (lane & 15);
    wBf[i] = f2bf(wdef[(size_t)o * 576 + c * 9 + tap]);
  }
  if (i < 18432) {
    int j = i & 7;
    int lane = (i >> 3) & 63;
    int n = (i >> 9) & 1;
    int kt = i >> 10;
    int kk = kt * 32 + ((lane >> 4) << 3) + j;
    int tap = kk >> 6, c = kk & 63;
    int o = (n << 4) + (lane & 15);
    wofBf[i] = (o < 18) ? f2bf(woff[((size_t)(o * 64 + c)) * 9 + tap]) : (unsigned short)0;
  }
  if (i < 32768) {
    int j = i & 7;
    int lane = (i >> 3) & 63;
    int n = (i >> 9) & 15;
    int kt = i >> 13;
    int c = kt * 32 + ((lane >> 4) << 3) + j;
    int o = (n << 4) + (lane & 15);
    w3Bf[i] = f2bf(w3[(size_t)o * 64 + c]);
  }
}

// ---- K1: conv1x1 256->64 via bf16 MFMA, double-buffered staging, bf16 NHWC + GN1 partials ----
__global__ __launch_bounds__(256) void k_conv1m(const float* __restrict__ x,
                                                const unsigned short* __restrict__ wA1f,
                                                unsigned short* __restrict__ xdT, float* __restrict__ ps) {
  __shared__ unsigned short xs[2][64][72];
  __shared__ float lds_s[4][32], lds_ss[4][32];
  int tid = threadIdx.x;
  int wave = tid >> 6, lane = tid & 63;
  int b = blockIdx.x >> 8;
  int chunk = blockIdx.x & 255;
  int px0 = chunk << 6;
  int pxl = lane & 15, q = lane >> 4;
  const float* xb = x + (size_t)b * 256 * HW + px0;
  const bf16x8* wAp = (const bf16x8*)wA1f;
  int sc = tid >> 4;
  int sq = tid & 15;
  f32x4 acc[4];
#pragma unroll
  for (int m = 0; m < 4; m++) acc[m] = (f32x4){0.f, 0.f, 0.f, 0.f};

  float4 vr[4];
#pragma unroll
  for (int r = 0; r < 4; r++)
    vr[r] = *(const float4*)(xb + (size_t)(r * 16 + sc) * HW + sq * 4);
#pragma unroll
  for (int r = 0; r < 4; r++) {
    int c = r * 16 + sc;
    xs[0][sq * 4 + 0][c] = f2bf(vr[r].x);
    xs[0][sq * 4 + 1][c] = f2bf(vr[r].y);
    xs[0][sq * 4 + 2][c] = f2bf(vr[r].z);
    xs[0][sq * 4 + 3][c] = f2bf(vr[r].w);
  }
  __syncthreads();

  for (int cb = 0; cb < 4; cb++) {
    int cur = cb & 1;
    if (cb < 3) {
#pragma unroll
      for (int r = 0; r < 4; r++)
        vr[r] = *(const float4*)(xb + (size_t)((cb + 1) * 64 + r * 16 + sc) * HW + sq * 4);
    }
#pragma unroll
    for (int kt = 0; kt < 2; kt++) {
      bf16x8 bfrag = *(const bf16x8*)&xs[cur][wave * 16 + pxl][kt * 32 + q * 8];
      int ktG = cb * 2 + kt;
#pragma unroll
      for (int m = 0; m < 4; m++) {
        bf16x8 af = wAp[(ktG * 4 + m) * 64 + lane];
        acc[m] = __builtin_amdgcn_mfma_f32_16x16x32_bf16(af, bfrag, acc[m], 0, 0, 0);
      }
    }
    if (cb < 3) {
#pragma unroll
      for (int r = 0; r < 4; r++) {
        int c = r * 16 + sc;
        xs[cur ^ 1][sq * 4 + 0][c] = f2bf(vr[r].x);
        xs[cur ^ 1][sq * 4 + 1][c] = f2bf(vr[r].y);
        xs[cur ^ 1][sq * 4 + 2][c] = f2bf(vr[r].z);
        xs[cur ^ 1][sq * 4 + 3][c] = f2bf(vr[r].w);
      }
    }
    __syncthreads();
  }
  unsigned short* xo = xdT + ((size_t)b * HW + px0 + wave * 16 + pxl) * 64 + (q << 2);
#pragma unroll
  for (int m = 0; m < 4; m++) {
    unsigned int u0, u1;
    asm("v_cvt_pk_bf16_f32 %0, %1, %2" : "=v"(u0) : "v"(acc[m][0]), "v"(acc[m][1]));
    asm("v_cvt_pk_bf16_f32 %0, %1, %2" : "=v"(u1) : "v"(acc[m][2]), "v"(acc[m][3]));
    *(uint2*)(xo + m * 16) = make_uint2(u0, u1);
  }
  float s[8], sq2[8];
#pragma unroll
  for (int m = 0; m < 4; m++)
#pragma unroll
    for (int h = 0; h < 2; h++) {
      float a = acc[m][2 * h] + acc[m][2 * h + 1];
      float qq = acc[m][2 * h] * acc[m][2 * h] + acc[m][2 * h + 1] * acc[m][2 * h + 1];
      s[m * 2 + h] = a; sq2[m * 2 + h] = qq;
    }
#pragma unroll
  for (int i = 0; i < 8; i++) {
#pragma unroll
    for (int off = 8; off; off >>= 1) {
      s[i] += __shfl_down(s[i], off, 16);
      sq2[i] += __shfl_down(sq2[i], off, 16);
    }
  }
  if (pxl == 0) {
#pragma unroll
    for (int i = 0; i < 8; i++) {
      int m = i >> 1, h = i & 1;
      int g = m * 8 + q * 2 + h;
      lds_s[wave][g] = s[i];
      lds_ss[wave][g] = sq2[i];
    }
  }
  __syncthreads();
  if (tid < 32) {
    float S = lds_s[0][tid] + lds_s[1][tid] + lds_s[2][tid] + lds_s[3][tid];
    float SS = lds_ss[0][tid] + lds_ss[1][tid] + lds_ss[2][tid] + lds_ss[3][tid];
    int bg = b * 32 + tid;
    ps[(bg * 256 + chunk) * 2] = S;
    ps[(bg * 256 + chunk) * 2 + 1] = SS;
  }
}

// ---- K2: finalize GN stats, block-parallel ----
__global__ __launch_bounds__(256) void k_gnfin_p(const float* __restrict__ ps, float* __restrict__ mrs,
                                                 int S, float n) {
  int bg = blockIdx.x;
  float s = 0.f, ss = 0.f;
  for (int i = threadIdx.x; i < S; i += 256) { s += ps[(bg * S + i) * 2]; ss += ps[(bg * S + i) * 2 + 1]; }
#pragma unroll
  for (int off = 32; off; off >>= 1) { s += __shfl_down(s, off); ss += __shfl_down(ss, off); }
  __shared__ float ls[4], lss[4];
  int wv = threadIdx.x >> 6;
  if ((threadIdx.x & 63) == 0) { ls[wv] = s; lss[wv] = ss; }
  __syncthreads();
  if (threadIdx.x == 0) {
    float Sa = ls[0] + ls[1] + ls[2] + ls[3];
    float SSa = lss[0] + lss[1] + lss[2] + lss[3];
    float mu = Sa / n;
    float var = SSa / n - mu * mu;
    mrs[bg] = mu;
    mrs[128 + bg] = rsqrtf(var + 1e-5f);
  }
}

// ---- K3: GN1 + ReLU in place on bf16 xdT ----
__global__ __launch_bounds__(256) void k_gnapply_bf(unsigned short* __restrict__ xdT,
                                                    const float* __restrict__ mrs,
                                                    const float* __restrict__ g1, const float* __restrict__ b1) {
  int i = blockIdx.x * 256 + threadIdx.x;
  int b = i >> 17;
  int ck = i & 7;
  int c0 = ck << 3;
  uint4 v = ((const uint4*)xdT)[i];
  float ga[8], be[8];
#pragma unroll
  for (int j = 0; j < 8; j += 2) {
    int g = (c0 + j) >> 1;
    float mu = mrs[b * 32 + g], rs = mrs[128 + b * 32 + g];
    ga[j] = g1[c0 + j] * rs;     be[j] = b1[c0 + j] - mu * ga[j];
    ga[j + 1] = g1[c0 + j + 1] * rs; be[j + 1] = b1[c0 + j + 1] - mu * ga[j + 1];
  }
  float r[8];
  r[0] = fmaxf(bflo(v.x) * ga[0] + be[0], 0.f);
  r[1] = fmaxf(bfhi(v.x) * ga[1] + be[1], 0.f);
  r[2] = fmaxf(bflo(v.y) * ga[2] + be[2], 0.f);
  r[3] = fmaxf(bfhi(v.y) * ga[3] + be[3], 0.f);
  r[4] = fmaxf(bflo(v.z) * ga[4] + be[4], 0.f);
  r[5] = fmaxf(bfhi(v.z) * ga[5] + be[5], 0.f);
  r[6] = fmaxf(bflo(v.w) * ga[6] + be[6], 0.f);
  r[7] = fmaxf(bfhi(v.w) * ga[7] + be[7], 0.f);
  uint4 o;
  asm("v_cvt_pk_bf16_f32 %0, %1, %2" : "=v"(o.x) : "v"(r[0]), "v"(r[1]));
  asm("v_cvt_pk_bf16_f32 %0, %1, %2" : "=v"(o.y) : "v"(r[2]), "v"(r[3]));
  asm("v_cvt_pk_bf16_f32 %0, %1, %2" : "=v"(o.z) : "v"(r[4]), "v"(r[5]));
  asm("v_cvt_pk_bf16_f32 %0, %1, %2" : "=v"(o.w) : "v"(r[6]), "v"(r[7]));
  ((uint4*)xdT)[i] = o;
}

// ---- K5: MEGA v6 — 8-wave block, offsL aliases A, tap 8 spread over waves 0-3 ----
__global__ __launch_bounds__(512, 8) void k_mega(const unsigned short* __restrict__ xdT,
                                                 const unsigned short* __restrict__ wofBf,
                                                 const unsigned short* __restrict__ wBf,
                                                 const unsigned short* __restrict__ w3Bf,
                                                 unsigned short* __restrict__ t3,
                                                 float* __restrict__ ps2) {
  __shared__ unsigned short A[36 * 65 * 8];  // 37,440 B; offsL aliases bytes [0,4608)
  float* offsL = (float*)A;
  int tid = threadIdx.x;
  int bb = blockIdx.x >> 8;
  int tileid = blockIdx.x & 255;
  int px0 = tileid << 6;
  const unsigned short* xtf = xdT + (size_t)bb * 64 * HW;  // bf16 NHWC (normalized)
  const char* xbt = (const char*)xtf;
  int wave = tid >> 6;  // 0..7
  int lane = tid & 63;
  int q16 = lane >> 2;
  int ch4 = lane & 3;
  int kq = lane >> 4;

  // ---- P0/P1: fixed-tap im2col build + off-GEMM; taps = wave (+ tap 8 via waves 0-3) ----
  f32x4 aoff = {0.f, 0.f, 0.f, 0.f};
  {
    int kyA = wave / 3 - 1, kxA = wave % 3 - 1;
    int kcbA = (wave * 4 + ch4) * 1040;
    int kcb8 = (32 + ch4) * 1040;
    int n2 = wave & 1;
    int mh1 = wave >> 1;
    int r1 = mh1 * 16 + (lane & 15);
    for (int h = 0; h < 2; ++h) {
      int co = (h << 6) + (ch4 << 4);
#pragma unroll
      for (int g = 0; g < 4; ++g) {
        int src = (g << 4) + q16;
        int px = px0 + src;
        int sy = (px >> 7) + kyA;
        int sx = (px & 127) + kxA;
        bool valid = ((unsigned)sy < 128u) && ((unsigned)sx < 128u);
        uint4 v = make_uint4(0u, 0u, 0u, 0u);
        if (valid) v = *(const uint4*)(xbt + (((sy << 7) + sx) << 7) + co);
        *(uint4*)((char*)A + kcbA + src * 16) = v;
      }
      if (wave < 4) {  // tap 8 (ky=1,kx=1): one px-group per wave
        int src = (wave << 4) + q16;
        int px = px0 + src;
        int sy = (px >> 7) + 1;
        int sx = (px & 127) + 1;
        bool valid = ((unsigned)sy < 128u) && ((unsigned)sx < 128u);
        uint4 v = make_uint4(0u, 0u, 0u, 0u);
        if (valid) v = *(const uint4*)(xbt + (((sy << 7) + sx) << 7) + co);
        *(uint4*)((char*)A + kcb8 + src * 16) = v;
      }
      __syncthreads();
      {
        const bf16x8* wp = (const bf16x8*)wofBf;
        __builtin_amdgcn_s_setprio(1);
#pragma unroll
        for (int tap = 0; tap < 9; ++tap) {
          bf16x8 bk = wp[((2 * tap + h) * 2 + n2) * 64 + lane];
          bf16x8 a0 = *(const bf16x8*)((const char*)A + ((tap * 4 + kq) * 65 + r1) * 16);
          aoff = __builtin_amdgcn_mfma_f32_16x16x32_bf16(a0, bk, aoff, 0, 0, 0);
        }
        __builtin_amdgcn_s_setprio(0);
      }
      __syncthreads();
    }
    // offsL write (aliases A; im2col content now dead)
    {
      int o = n2 * 16 + (lane & 15);
      if (o < 18) {
        int prow = mh1 * 16 + ((lane >> 4) << 2);
#pragma unroll
        for (int r = 0; r < 4; r++) offsL[(prow + r) * 18 + o] = aoff[r];
      }
    }
  }
  __syncthreads();  // offsL ready

  // ---- P2: geometry. geomA: (pxl=lane, tap=wave). geomB (waves 0-3): (pxl=lane, tap=8) ----
  float w00, w01, w10, w11;
  int a00, a01, a10, a11;
  {
    int px = px0 + lane;
    int y = px >> 7, xc = px & 127;
    float dy = offsL[lane * 18 + 2 * wave];
    float dx = offsL[lane * 18 + 2 * wave + 1];
    float py = (float)(y + wave / 3 - 1) + dy;
    float pxx = (float)(xc + wave % 3 - 1) + dx;
    float y0f = floorf(py), x0f = floorf(pxx);
    float ay = py - y0f, ax = pxx - x0f;
    int y0 = (int)y0f, x0 = (int)x0f;
    int y1i = y0 + 1, x1i = x0 + 1;
    float by0 = 1.f - ay, bx0 = 1.f - ax;
    bool vy0 = (unsigned)y0 < 128u, vy1 = (unsigned)y1i < 128u;
    bool vx0 = (unsigned)x0 < 128u, vx1 = (unsigned)x1i < 128u;
    w00 = (vy0 && vx0) ? by0 * bx0 : 0.f;
    w01 = (vy0 && vx1) ? by0 * ax : 0.f;
    w10 = (vy1 && vx0) ? ay * bx0 : 0.f;
    w11 = (vy1 && vx1) ? ay * ax : 0.f;
    int iy0 = min(max(y0, 0), 127), iy1 = min(max(y1i, 0), 127);
    int ix0 = min(max(x0, 0), 127), ix1 = min(max(x1i, 0), 127);
    a00 = (iy0 * WIDTH + ix0) << 7;
    a01 = (iy0 * WIDTH + ix1) << 7;
    a10 = (iy1 * WIDTH + ix0) << 7;
    a11 = (iy1 * WIDTH + ix1) << 7;
  }
  float e00 = 0.f, e01 = 0.f, e10 = 0.f, e11 = 0.f;
  int b00 = 0, b01 = 0, b10 = 0, b11 = 0;
  if (wave < 4) {  // tap 8
    int px = px0 + lane;
    int y = px >> 7, xc = px & 127;
    float dy = offsL[lane * 18 + 16];
    float dx = offsL[lane * 18 + 17];
    float py = (float)(y + 1) + dy;
    float pxx = (float)(xc + 1) + dx;
    float y0f = floorf(py), x0f = floorf(pxx);
    float ay = py - y0f, ax = pxx - x0f;
    int y0 = (int)y0f, x0 = (int)x0f;
    int y1i = y0 + 1, x1i = x0 + 1;
    float by0 = 1.f - ay, bx0 = 1.f - ax;
    bool vy0 = (unsigned)y0 < 128u, vy1 = (unsigned)y1i < 128u;
    bool vx0 = (unsigned)x0 < 128u, vx1 = (unsigned)x1i < 128u;
    e00 = (vy0 && vx0) ? by0 * bx0 : 0.f;
    e01 = (vy0 && vx1) ? by0 * ax : 0.f;
    e10 = (vy1 && vx0) ? ay * bx0 : 0.f;
    e11 = (vy1 && vx1) ? ay * ax : 0.f;
    int iy0 = min(max(y0, 0), 127), iy1 = min(max(y1i, 0), 127);
    int ix0 = min(max(x0, 0), 127), ix1 = min(max(x1i, 0), 127);
    b00 = (iy0 * WIDTH + ix0) << 7;
    b01 = (iy0 * WIDTH + ix1) << 7;
    b10 = (iy1 * WIDTH + ix0) << 7;
    b11 = (iy1 * WIDTH + ix1) << 7;
  }
  __syncthreads();  // all offsL reads complete before P3 overwrites A

  // ---- P3/P4: bilinear build + GEMM1, two channel halves; + residual, A2 ----
  int n1 = wave & 3;
  int mh = wave >> 2;
  f32x4 acc0 = {0.f, 0.f, 0.f, 0.f};
  f32x4 acc1 = {0.f, 0.f, 0.f, 0.f};
  int kcbA = (wave * 4 + ch4) * 1040;
  int kcb8 = (32 + ch4) * 1040;
  for (int h = 0; h < 2; ++h) {
    int co = (h << 6) + (ch4 << 4);
#pragma unroll
    for (int g = 0; g < 4; ++g) {
      int src = (g << 4) + q16;
      float j0 = __shfl(w00, src), j1 = __shfl(w01, src);
      float j2 = __shfl(w10, src), j3 = __shfl(w11, src);
      int c0 = __shfl(a00, src), c1 = __shfl(a01, src);
      int c2 = __shfl(a10, src), c3 = __shfl(a11, src);
      uint4 v0 = *(const uint4*)(xbt + c0 + co);
      uint4 v1 = *(const uint4*)(xbt + c1 + co);
      uint4 v2 = *(const uint4*)(xbt + c2 + co);
      uint4 v3 = *(const uint4*)(xbt + c3 + co);
      float r[8];
      r[0] = j0 * bflo(v0.x) + j1 * bflo(v1.x) + j2 * bflo(v2.x) + j3 * bflo(v3.x);
      r[1] = j0 * bfhi(v0.x) + j1 * bfhi(v1.x) + j2 * bfhi(v2.x) + j3 * bfhi(v3.x);
      r[2] = j0 * bflo(v0.y) + j1 * bflo(v1.y) + j2 * bflo(v2.y) + j3 * bflo(v3.y);
      r[3] = j0 * bfhi(v0.y) + j1 * bfhi(v1.y) + j2 * bfhi(v2.y) + j3 * bfhi(v3.y);
      r[4] = j0 * bflo(v0.z) + j1 * bflo(v1.z) + j2 * bflo(v2.z) + j3 * bflo(v3.z);
      r[5] = j0 * bfhi(v0.z) + j1 * bfhi(v1.z) + j2 * bfhi(v2.z) + j3 * bfhi(v3.z);
      r[6] = j0 * bflo(v0.w) + j1 * bflo(v1.w) + j2 * bflo(v2.w) + j3 * bflo(v3.w);
      r[7] = j0 * bfhi(v0.w) + j1 * bfhi(v1.w) + j2 * bfhi(v2.w) + j3 * bfhi(v3.w);
      uint4 ov;
      asm("v_cvt_pk_bf16_f32 %0, %1, %2" : "=v"(ov.x) : "v"(r[0]), "v"(r[1]));
      asm("v_cvt_pk_bf16_f32 %0, %1, %2" : "=v"(ov.y) : "v"(r[2]), "v"(r[3]));
      asm("v_cvt_pk_bf16_f32 %0, %1, %2" : "=v"(ov.z) : "v"(r[4]), "v"(r[5]));
      asm("v_cvt_pk_bf16_f32 %0, %1, %2" : "=v"(ov.w) : "v"(r[6]), "v"(r[7]));
      *(uint4*)((char*)A + kcbA + src * 16) = ov;
    }
    if (wave < 4) {  // tap 8: one px-group per wave
      int src = (wave << 4) + q16;
      float j0 = __shfl(e00, src), j1 = __shfl(e01, src);
      float j2 = __shfl(e10, src), j3 = __shfl(e11, src);
      int c0 = __shfl(b00, src), c1 = __shfl(b01, src);
      int c2 = __shfl(b10, src), c3 = __shfl(b11, src);
      uint4 v0 = *(const uint4*)(xbt + c0 + co);
      uint4 v1 = *(const uint4*)(xbt + c1 + co);
      uint4 v2 = *(const uint4*)(xbt + c2 + co);
      uint4 v3 = *(const uint4*)(xbt + c3 + co);
      float r[8];
      r[0] = j0 * bflo(v0.x) + j1 * bflo(v1.x) + j2 * bflo(v2.x) + j3 * bflo(v3.x);
      r[1] = j0 * bfhi(v0.x) + j1 * bfhi(v1.x) + j2 * bfhi(v2.x) + j3 * bfhi(v3.x);
      r[2] = j0 * bflo(v0.y) + j1 * bflo(v1.y) + j2 * bflo(v2.y) + j3 * bflo(v3.y);
      r[3] = j0 * bfhi(v0.y) + j1 * bfhi(v1.y) + j2 * bfhi(v2.y) + j3 * bfhi(v3.y);
      r[4] = j0 * bflo(v0.z) + j1 * bflo(v1.z) + j2 * bflo(v2.z) + j3 * bflo(v3.z);
      r[5] = j0 * bfhi(v0.z) + j1 * bfhi(v1.z) + j2 * bfhi(v2.z) + j3 * bfhi(v3.z);
      r[6] = j0 * bflo(v0.w) + j1 * bflo(v1.w) + j2 * bflo(v2.w) + j3 * bflo(v3.w);
      r[7] = j0 * bfhi(v0.w) + j1 * bfhi(v1.w) + j2 * bfhi(v2.w) + j3 * bfhi(v3.w);
      uint4 ov;
      asm("v_cvt_pk_bf16_f32 %0, %1, %2" : "=v"(ov.x) : "v"(r[0]), "v"(r[1]));
      asm("v_cvt_pk_bf16_f32 %0, %1, %2" : "=v"(ov.y) : "v"(r[2]), "v"(r[3]));
      asm("v_cvt_pk_bf16_f32 %0, %1, %2" : "=v"(ov.z) : "v"(r[4]), "v"(r[5]));
      asm("v_cvt_pk_bf16_f32 %0, %1, %2" : "=v"(ov.w) : "v"(r[6]), "v"(r[7]));
      *(uint4*)((char*)A + kcb8 + src * 16) = ov;
    }
    __syncthreads();
    {
      int r0r = mh * 32 + (lane & 15);
      const bf16x8* wp = (const bf16x8*)wBf;
      __builtin_amdgcn_s_setprio(1);
#pragma unroll
      for (int tap = 0; tap < 9; ++tap) {
        bf16x8 bk = wp[((2 * tap + h) * 4 + n1) * 64 + lane];
        int kc = tap * 4 + kq;
        bf16x8 a0 = *(const bf16x8*)((const char*)A + (kc * 65 + r0r) * 16);
        bf16x8 a1 = *(const bf16x8*)((const char*)A + (kc * 65 + r0r + 16) * 16);
        acc0 = __builtin_amdgcn_mfma_f32_16x16x32_bf16(a0, bk, acc0, 0, 0, 0);
        acc1 = __builtin_amdgcn_mfma_f32_16x16x32_bf16(a1, bk, acc1, 0, 0, 0);
      }
      __builtin_amdgcn_s_setprio(0);
    }
    __syncthreads();
  }
  // residual (bf16 unpack) + A2 write
  {
    int c = n1 * 16 + (lane & 15);
    int pb = px0 + mh * 32 + ((lane >> 4) << 2);
#pragma unroll
    for (int r = 0; r < 4; r++) {
      acc0[r] += __uint_as_float((unsigned int)xtf[(size_t)(pb + r) * 64 + c] << 16);
      acc1[r] += __uint_as_float((unsigned int)xtf[(size_t)(pb + 16 + r) * 64 + c] << 16);
    }
    char* base = (char*)A + (c >> 3) * 1040 + (c & 7) * 2;
    int pxr = mh * 32 + ((lane >> 4) << 2);
#pragma unroll
    for (int r = 0; r < 4; r++) {
      *(unsigned short*)(base + (size_t)(pxr + r) * 16) = f2bf(acc0[r]);
      *(unsigned short*)(base + (size_t)(pxr + 16 + r) * 16) = f2bf(acc1[r]);
    }
  }
  __syncthreads();

  // ---- P6: GEMM2 (M=64, N=256, K=64) + GN2 partials + bf16 t3 ----
  f32x4 cA[4], cB[4];
#pragma unroll
  for (int ni = 0; ni < 4; ni++) {
    cA[ni] = (f32x4){0.f, 0.f, 0.f, 0.f};
    cB[ni] = (f32x4){0.f, 0.f, 0.f, 0.f};
  }
  {
    int mt0 = (wave >> 2) * 2;
    const bf16x8* wp2 = (const bf16x8*)w3Bf;
    __builtin_amdgcn_s_setprio(1);
#pragma unroll
    for (int kt = 0; kt < 2; kt++) {
      int kc = kt * 4 + kq;
      bf16x8 aA = *(const bf16x8*)((const char*)A + (size_t)(kc * 65 + mt0 * 16 + (lane & 15)) * 16);
      bf16x8 aB = *(const bf16x8*)((const char*)A + (size_t)(kc * 65 + (mt0 + 1) * 16 + (lane & 15)) * 16);
#pragma unroll
      for (int ni = 0; ni < 4; ni++) {
        int ng = n1 * 4 + ni;
        bf16x8 bk = wp2[(kt * 16 + ng) * 64 + lane];
        cA[ni] = __builtin_amdgcn_mfma_f32_16x16x32_bf16(aA, bk, cA[ni], 0, 0, 0);
        cB[ni] = __builtin_amdgcn_mfma_f32_16x16x32_bf16(aB, bk, cB[ni], 0, 0, 0);
      }
    }
    __builtin_amdgcn_s_setprio(0);
  }
#pragma unroll
  for (int ni = 0; ni < 4; ni++) {
    float s = 0.f, qq = 0.f;
#pragma unroll
    for (int r = 0; r < 4; r++) {
      float v0 = cA[ni][r], v1 = cB[ni][r];
      s += v0 + v1; qq += v0 * v0 + v1 * v1;
    }
    s += __shfl_down(s, 32); qq += __shfl_down(qq, 32);
    s += __shfl_down(s, 16); qq += __shfl_down(qq, 16);
    s += __shfl_down(s, 4);  qq += __shfl_down(qq, 4);
    s += __shfl_down(s, 2);  qq += __shfl_down(qq, 2);
    s += __shfl_down(s, 1);  qq += __shfl_down(qq, 1);
    if (lane == 0 || lane == 8) {
      int g = (n1 * 4 + ni) * 2 + (lane >> 3);
      int slot = ((bb * 32 + g) * 256 + tileid) * 2 + (wave >> 2);
      ps2[slot * 2] = s;
      ps2[slot * 2 + 1] = qq;
    }
  }
  unsigned short* tb = t3 + (size_t)bb * 256 * HW + px0;
  int mtq = (wave >> 2) * 32 + ((lane >> 4) << 2);
#pragma unroll
  for (int ni = 0; ni < 4; ni++) {
    int o = (n1 * 4 + ni) * 16 + (lane & 15);
    unsigned short* p0 = tb + (size_t)o * HW + mtq;
    unsigned int u0, u1, u2, u3;
    asm("v_cvt_pk_bf16_f32 %0, %1, %2" : "=v"(u0) : "v"(cA[ni][0]), "v"(cA[ni][1]));
    asm("v_cvt_pk_bf16_f32 %0, %1, %2" : "=v"(u1) : "v"(cA[ni][2]), "v"(cA[ni][3]));
    asm("v_cvt_pk_bf16_f32 %0, %1, %2" : "=v"(u2) : "v"(cB[ni][0]), "v"(cB[ni][1]));
    asm("v_cvt_pk_bf16_f32 %0, %1, %2" : "=v"(u3) : "v"(cB[ni][2]), "v"(cB[ni][3]));
    *(uint2*)p0 = make_uint2(u0, u1);
    *(uint2*)(p0 + 16) = make_uint2(u2, u3);
  }
}

// ---- K8: out = relu(gn2(t3_bf16)) + x ----
__global__ __launch_bounds__(256) void k_final(const unsigned short* __restrict__ t3, const float* __restrict__ x,
                                               const float* __restrict__ mrs, const float* __restrict__ g3,
                                               const float* __restrict__ b3, float* __restrict__ out) {
  int i4 = blockIdx.x * 256 + threadIdx.x;
  int b = i4 >> 20;
  int c = (i4 >> 12) & 255;
  int g = c >> 3;
  float mu = mrs[b * 32 + g], rs = mrs[128 + b * 32 + g];
  float ga = g3[c] * rs, be = b3[c] - mu * ga;
  uint2 tv = ((const uint2*)t3)[i4];
  float t0 = bflo(tv.x);
  float t1 = bfhi(tv.x);
  float t2 = bflo(tv.y);
  float t3v = bfhi(tv.y);
  float4 xv = ((const float4*)x)[i4];
  float4 r;
  r.x = fmaxf(t0 * ga + be, 0.f) + xv.x;
  r.y = fmaxf(t1 * ga + be, 0.f) + xv.y;
  r.z = fmaxf(t2 * ga + be, 0.f) + xv.z;
  r.w = fmaxf(t3v * ga + be, 0.f) + xv.w;
  ((float4*)out)[i4] = r;
}

extern "C" void kernel_launch(void* const* d_in, const int* in_sizes, int n_in,
                              void* d_out, int out_size, void* d_ws, size_t ws_size,
                              hipStream_t stream) {
  const float* x    = (const float*)d_in[0];
  const float* w1   = (const float*)d_in[1];
  const float* g1   = (const float*)d_in[2];
  const float* b1   = (const float*)d_in[3];
  const float* woff = (const float*)d_in[4];
  const float* wdef = (const float*)d_in[5];
  const float* w3   = (const float*)d_in[6];
  const float* g3   = (const float*)d_in[7];
  const float* b3   = (const float*)d_in[8];
  float* ws = (float*)d_ws;

  unsigned short* xdT = (unsigned short*)ws;               // 4,194,304 ush = 2,097,152 fl
  unsigned short* t3  = (unsigned short*)(ws + 2097152);   // 16,777,216 ush = 8,388,608 fl
  float* base = ws + 2097152 + 8388608;
  float* mrs1 = base;                     // 256
  float* mrs2 = mrs1 + 256;               // 256
  unsigned short* wA1f  = (unsigned short*)(mrs2 + 256);                        // 8,192 fl
  unsigned short* wBf   = (unsigned short*)(mrs2 + 256 + 8192);                 // 18,432 fl
  unsigned short* wofBf = (unsigned short*)(mrs2 + 256 + 8192 + 18432);         // 9,216 fl
  unsigned short* w3Bf  = (unsigned short*)(mrs2 + 256 + 8192 + 18432 + 9216);  // 16,384 fl
  float* ps   = mrs2 + 256 + 8192 + 18432 + 9216 + 16384;  // 65,536
  float* ps2  = ps + 65536;               // 131,072
  float* out  = (float*)d_out;

  hipLaunchKernelGGL(k_prep, dim3(144), dim3(256), 0, stream, w1, w3, wdef, woff, wA1f, wBf, wofBf, w3Bf);
  hipLaunchKernelGGL(k_conv1m, dim3(1024), dim3(256), 0, stream, x, wA1f, xdT, ps);
  hipLaunchKernelGGL(k_gnfin_p, dim3(128), dim3(256), 0, stream, ps, mrs1, 256, (float)(2 * HW));
  hipLaunchKernelGGL(k_gnapply_bf, dim3(2048), dim3(256), 0, stream, xdT, mrs1, g1, b1);
  hipLaunchKernelGGL(k_mega, dim3(1024), dim3(512), 0, stream, xdT, wofBf, wBf, w3Bf, t3, ps2);
  hipLaunchKernelGGL(k_gnfin_p, dim3(128), dim3(256), 0, stream, ps2, mrs2, 512, 131072.f);
  hipLaunchKernelGGL(k_final, dim3(16384), dim3(256), 0, stream, t3, x, mrs2, g3, b3, out);
}

// Round 19
// 103.662 us; speedup vs baseline: 1.4860x; 1.0835x over previous
//
#include <hip/hip_runtime.h>

// deformMP: B=4, Cc=256, ci=64, H=W=128, GN groups=32, eps=1e-5
// ws: xdTbf[2.10M fl-equiv NHWC bf16] t3bf[8.39M] mrs1/2 wA1f wBf wofBf w3Bf ps ps2
// k_mega v7 = v6 (8-wave blocks, offsL aliases A) + P6 split into 2 n-half passes
// (peak regs fit 64 @ 8 waves/SIMD, no spill) + batch-L2 swizzle (bb = blk&3 so the
// 4 co-resident blocks/CU share one batch -> xdT L2-resident).

#define HW 16384
#define WIDTH 128

typedef __attribute__((ext_vector_type(8))) short bf16x8;
typedef __attribute__((ext_vector_type(4))) float f32x4;

__device__ __forceinline__ unsigned short f2bf(float f) {
  unsigned int u = __float_as_uint(f);
  u = (u + 0x7fffu + ((u >> 16) & 1u)) >> 16;  // RNE
  return (unsigned short)u;
}
__device__ __forceinline__ float bflo(unsigned int u) { return __uint_as_float(u << 16); }
__device__ __forceinline__ float bfhi(unsigned int u) { return __uint_as_float(u & 0xffff0000u); }

// ---- K0: weight repack (unchanged) ----
__global__ __launch_bounds__(256) void k_prep(const float* __restrict__ w1, const float* __restrict__ w3,
                                              const float* __restrict__ wdef, const float* __restrict__ woff,
                                              unsigned short* __restrict__ wA1f,
                                              unsigned short* __restrict__ wBf,
                                              unsigned short* __restrict__ wofBf,
                                              unsigned short* __restrict__ w3Bf) {
  int i = blockIdx.x * 256 + threadIdx.x;
  if (i < 16384) {
    int j = i & 7;
    int lane = (i >> 3) & 63;
    int m = (i >> 9) & 3;
    int kt = i >> 11;
    int o = (m << 4) + (lane & 15);
    int c = kt * 32 + ((lane >> 4) << 3) + j;
    wA1f[i] = f2bf(w1[(size_t)o * 256 + c]);
  }
  if (i < 36864) {
    int j = i & 7;
    int lane = (i >> 3) & 63;
    int n = (i >> 9) & 3;
    int kt = i >> 11;
    int kk = kt * 32 + ((lane >> 4) << 3) + j;
    int tap = kk >> 6, c = kk & 63;
    int o = (n << 4) + (lane & 15);
    wBf[i] = f2bf(wdef[(size_t)o * 576 + c * 9 + tap]);
  }
  if (i < 18432) {
    int j = i & 7;
    int lane = (i >> 3) & 63;
    int n = (i >> 9) & 1;
    int kt = i >> 10;
    int kk = kt * 32 + ((lane >> 4) << 3) + j;
    int tap = kk >> 6, c = kk & 63;
    int o = (n << 4) + (lane & 15);
    wofBf[i] = (o < 18) ? f2bf(woff[((size_t)(o * 64 + c)) * 9 + tap]) : (unsigned short)0;
  }
  if (i < 32768) {
    int j = i & 7;
    int lane = (i >> 3) & 63;
    int n = (i >> 9) & 15;
    int kt = i >> 13;
    int c = kt * 32 + ((lane >> 4) << 3) + j;
    int o = (n << 4) + (lane & 15);
    w3Bf[i] = f2bf(w3[(size_t)o * 64 + c]);
  }
}

// ---- K1: conv1x1 256->64 via bf16 MFMA, double-buffered staging, bf16 NHWC + GN1 partials ----
__global__ __launch_bounds__(256) void k_conv1m(const float* __restrict__ x,
                                                const unsigned short* __restrict__ wA1f,
                                                unsigned short* __restrict__ xdT, float* __restrict__ ps) {
  __shared__ unsigned short xs[2][64][72];
  __shared__ float lds_s[4][32], lds_ss[4][32];
  int tid = threadIdx.x;
  int wave = tid >> 6, lane = tid & 63;
  int b = blockIdx.x >> 8;
  int chunk = blockIdx.x & 255;
  int px0 = chunk << 6;
  int pxl = lane & 15, q = lane >> 4;
  const float* xb = x + (size_t)b * 256 * HW + px0;
  const bf16x8* wAp = (const bf16x8*)wA1f;
  int sc = tid >> 4;
  int sq = tid & 15;
  f32x4 acc[4];
#pragma unroll
  for (int m = 0; m < 4; m++) acc[m] = (f32x4){0.f, 0.f, 0.f, 0.f};

  float4 vr[4];
#pragma unroll
  for (int r = 0; r < 4; r++)
    vr[r] = *(const float4*)(xb + (size_t)(r * 16 + sc) * HW + sq * 4);
#pragma unroll
  for (int r = 0; r < 4; r++) {
    int c = r * 16 + sc;
    xs[0][sq * 4 + 0][c] = f2bf(vr[r].x);
    xs[0][sq * 4 + 1][c] = f2bf(vr[r].y);
    xs[0][sq * 4 + 2][c] = f2bf(vr[r].z);
    xs[0][sq * 4 + 3][c] = f2bf(vr[r].w);
  }
  __syncthreads();

  for (int cb = 0; cb < 4; cb++) {
    int cur = cb & 1;
    if (cb < 3) {
#pragma unroll
      for (int r = 0; r < 4; r++)
        vr[r] = *(const float4*)(xb + (size_t)((cb + 1) * 64 + r * 16 + sc) * HW + sq * 4);
    }
#pragma unroll
    for (int kt = 0; kt < 2; kt++) {
      bf16x8 bfrag = *(const bf16x8*)&xs[cur][wave * 16 + pxl][kt * 32 + q * 8];
      int ktG = cb * 2 + kt;
#pragma unroll
      for (int m = 0; m < 4; m++) {
        bf16x8 af = wAp[(ktG * 4 + m) * 64 + lane];
        acc[m] = __builtin_amdgcn_mfma_f32_16x16x32_bf16(af, bfrag, acc[m], 0, 0, 0);
      }
    }
    if (cb < 3) {
#pragma unroll
      for (int r = 0; r < 4; r++) {
        int c = r * 16 + sc;
        xs[cur ^ 1][sq * 4 + 0][c] = f2bf(vr[r].x);
        xs[cur ^ 1][sq * 4 + 1][c] = f2bf(vr[r].y);
        xs[cur ^ 1][sq * 4 + 2][c] = f2bf(vr[r].z);
        xs[cur ^ 1][sq * 4 + 3][c] = f2bf(vr[r].w);
      }
    }
    __syncthreads();
  }
  unsigned short* xo = xdT + ((size_t)b * HW + px0 + wave * 16 + pxl) * 64 + (q << 2);
#pragma unroll
  for (int m = 0; m < 4; m++) {
    unsigned int u0, u1;
    asm("v_cvt_pk_bf16_f32 %0, %1, %2" : "=v"(u0) : "v"(acc[m][0]), "v"(acc[m][1]));
    asm("v_cvt_pk_bf16_f32 %0, %1, %2" : "=v"(u1) : "v"(acc[m][2]), "v"(acc[m][3]));
    *(uint2*)(xo + m * 16) = make_uint2(u0, u1);
  }
  float s[8], sq2[8];
#pragma unroll
  for (int m = 0; m < 4; m++)
#pragma unroll
    for (int h = 0; h < 2; h++) {
      float a = acc[m][2 * h] + acc[m][2 * h + 1];
      float qq = acc[m][2 * h] * acc[m][2 * h] + acc[m][2 * h + 1] * acc[m][2 * h + 1];
      s[m * 2 + h] = a; sq2[m * 2 + h] = qq;
    }
#pragma unroll
  for (int i = 0; i < 8; i++) {
#pragma unroll
    for (int off = 8; off; off >>= 1) {
      s[i] += __shfl_down(s[i], off, 16);
      sq2[i] += __shfl_down(sq2[i], off, 16);
    }
  }
  if (pxl == 0) {
#pragma unroll
    for (int i = 0; i < 8; i++) {
      int m = i >> 1, h = i & 1;
      int g = m * 8 + q * 2 + h;
      lds_s[wave][g] = s[i];
      lds_ss[wave][g] = sq2[i];
    }
  }
  __syncthreads();
  if (tid < 32) {
    float S = lds_s[0][tid] + lds_s[1][tid] + lds_s[2][tid] + lds_s[3][tid];
    float SS = lds_ss[0][tid] + lds_ss[1][tid] + lds_ss[2][tid] + lds_ss[3][tid];
    int bg = b * 32 + tid;
    ps[(bg * 256 + chunk) * 2] = S;
    ps[(bg * 256 + chunk) * 2 + 1] = SS;
  }
}

// ---- K2: finalize GN stats, block-parallel ----
__global__ __launch_bounds__(256) void k_gnfin_p(const float* __restrict__ ps, float* __restrict__ mrs,
                                                 int S, float n) {
  int bg = blockIdx.x;
  float s = 0.f, ss = 0.f;
  for (int i = threadIdx.x; i < S; i += 256) { s += ps[(bg * S + i) * 2]; ss += ps[(bg * S + i) * 2 + 1]; }
#pragma unroll
  for (int off = 32; off; off >>= 1) { s += __shfl_down(s, off); ss += __shfl_down(ss, off); }
  __shared__ float ls[4], lss[4];
  int wv = threadIdx.x >> 6;
  if ((threadIdx.x & 63) == 0) { ls[wv] = s; lss[wv] = ss; }
  __syncthreads();
  if (threadIdx.x == 0) {
    float Sa = ls[0] + ls[1] + ls[2] + ls[3];
    float SSa = lss[0] + lss[1] + lss[2] + lss[3];
    float mu = Sa / n;
    float var = SSa / n - mu * mu;
    mrs[bg] = mu;
    mrs[128 + bg] = rsqrtf(var + 1e-5f);
  }
}

// ---- K3: GN1 + ReLU in place on bf16 xdT ----
__global__ __launch_bounds__(256) void k_gnapply_bf(unsigned short* __restrict__ xdT,
                                                    const float* __restrict__ mrs,
                                                    const float* __restrict__ g1, const float* __restrict__ b1) {
  int i = blockIdx.x * 256 + threadIdx.x;
  int b = i >> 17;
  int ck = i & 7;
  int c0 = ck << 3;
  uint4 v = ((const uint4*)xdT)[i];
  float ga[8], be[8];
#pragma unroll
  for (int j = 0; j < 8; j += 2) {
    int g = (c0 + j) >> 1;
    float mu = mrs[b * 32 + g], rs = mrs[128 + b * 32 + g];
    ga[j] = g1[c0 + j] * rs;     be[j] = b1[c0 + j] - mu * ga[j];
    ga[j + 1] = g1[c0 + j + 1] * rs; be[j + 1] = b1[c0 + j + 1] - mu * ga[j + 1];
  }
  float r[8];
  r[0] = fmaxf(bflo(v.x) * ga[0] + be[0], 0.f);
  r[1] = fmaxf(bfhi(v.x) * ga[1] + be[1], 0.f);
  r[2] = fmaxf(bflo(v.y) * ga[2] + be[2], 0.f);
  r[3] = fmaxf(bfhi(v.y) * ga[3] + be[3], 0.f);
  r[4] = fmaxf(bflo(v.z) * ga[4] + be[4], 0.f);
  r[5] = fmaxf(bfhi(v.z) * ga[5] + be[5], 0.f);
  r[6] = fmaxf(bflo(v.w) * ga[6] + be[6], 0.f);
  r[7] = fmaxf(bfhi(v.w) * ga[7] + be[7], 0.f);
  uint4 o;
  asm("v_cvt_pk_bf16_f32 %0, %1, %2" : "=v"(o.x) : "v"(r[0]), "v"(r[1]));
  asm("v_cvt_pk_bf16_f32 %0, %1, %2" : "=v"(o.y) : "v"(r[2]), "v"(r[3]));
  asm("v_cvt_pk_bf16_f32 %0, %1, %2" : "=v"(o.z) : "v"(r[4]), "v"(r[5]));
  asm("v_cvt_pk_bf16_f32 %0, %1, %2" : "=v"(o.w) : "v"(r[6]), "v"(r[7]));
  ((uint4*)xdT)[i] = o;
}

// ---- K5: MEGA v7 — 8-wave block, offsL aliases A, P6 two-pass, batch-L2 swizzle ----
__global__ __launch_bounds__(512, 8) void k_mega(const unsigned short* __restrict__ xdT,
                                                 const unsigned short* __restrict__ wofBf,
                                                 const unsigned short* __restrict__ wBf,
                                                 const unsigned short* __restrict__ w3Bf,
                                                 unsigned short* __restrict__ t3,
                                                 float* __restrict__ ps2) {
  __shared__ unsigned short A[36 * 65 * 8];  // 37,440 B; offsL aliases bytes [0,4608)
  float* offsL = (float*)A;
  int tid = threadIdx.x;
  int bb = blockIdx.x & 3;          // batch-L2 swizzle: co-resident blocks share batch
  int tileid = blockIdx.x >> 2;
  int px0 = tileid << 6;
  const unsigned short* xtf = xdT + (size_t)bb * 64 * HW;  // bf16 NHWC (normalized)
  const char* xbt = (const char*)xtf;
  int wave = tid >> 6;  // 0..7
  int lane = tid & 63;
  int q16 = lane >> 2;
  int ch4 = lane & 3;
  int kq = lane >> 4;

  // ---- P0/P1: fixed-tap im2col build + off-GEMM; taps = wave (+ tap 8 via waves 0-3) ----
  f32x4 aoff = {0.f, 0.f, 0.f, 0.f};
  {
    int kyA = wave / 3 - 1, kxA = wave % 3 - 1;
    int kcbA = (wave * 4 + ch4) * 1040;
    int kcb8 = (32 + ch4) * 1040;
    int n2 = wave & 1;
    int mh1 = wave >> 1;
    int r1 = mh1 * 16 + (lane & 15);
    for (int h = 0; h < 2; ++h) {
      int co = (h << 6) + (ch4 << 4);
#pragma unroll
      for (int g = 0; g < 4; ++g) {
        int src = (g << 4) + q16;
        int px = px0 + src;
        int sy = (px >> 7) + kyA;
        int sx = (px & 127) + kxA;
        bool valid = ((unsigned)sy < 128u) && ((unsigned)sx < 128u);
        uint4 v = make_uint4(0u, 0u, 0u, 0u);
        if (valid) v = *(const uint4*)(xbt + (((sy << 7) + sx) << 7) + co);
        *(uint4*)((char*)A + kcbA + src * 16) = v;
      }
      if (wave < 4) {  // tap 8 (ky=1,kx=1): one px-group per wave
        int src = (wave << 4) + q16;
        int px = px0 + src;
        int sy = (px >> 7) + 1;
        int sx = (px & 127) + 1;
        bool valid = ((unsigned)sy < 128u) && ((unsigned)sx < 128u);
        uint4 v = make_uint4(0u, 0u, 0u, 0u);
        if (valid) v = *(const uint4*)(xbt + (((sy << 7) + sx) << 7) + co);
        *(uint4*)((char*)A + kcb8 + src * 16) = v;
      }
      __syncthreads();
      {
        const bf16x8* wp = (const bf16x8*)wofBf;
        __builtin_amdgcn_s_setprio(1);
#pragma unroll
        for (int tap = 0; tap < 9; ++tap) {
          bf16x8 bk = wp[((2 * tap + h) * 2 + n2) * 64 + lane];
          bf16x8 a0 = *(const bf16x8*)((const char*)A + ((tap * 4 + kq) * 65 + r1) * 16);
          aoff = __builtin_amdgcn_mfma_f32_16x16x32_bf16(a0, bk, aoff, 0, 0, 0);
        }
        __builtin_amdgcn_s_setprio(0);
      }
      __syncthreads();
    }
    // offsL write (aliases A; im2col content now dead)
    {
      int o = n2 * 16 + (lane & 15);
      if (o < 18) {
        int prow = mh1 * 16 + ((lane >> 4) << 2);
#pragma unroll
        for (int r = 0; r < 4; r++) offsL[(prow + r) * 18 + o] = aoff[r];
      }
    }
  }
  __syncthreads();  // offsL ready

  // ---- P2: geometry. geomA: (pxl=lane, tap=wave). geomB (waves 0-3): (pxl=lane, tap=8) ----
  float w00, w01, w10, w11;
  int a00, a01, a10, a11;
  {
    int px = px0 + lane;
    int y = px >> 7, xc = px & 127;
    float dy = offsL[lane * 18 + 2 * wave];
    float dx = offsL[lane * 18 + 2 * wave + 1];
    float py = (float)(y + wave / 3 - 1) + dy;
    float pxx = (float)(xc + wave % 3 - 1) + dx;
    float y0f = floorf(py), x0f = floorf(pxx);
    float ay = py - y0f, ax = pxx - x0f;
    int y0 = (int)y0f, x0 = (int)x0f;
    int y1i = y0 + 1, x1i = x0 + 1;
    float by0 = 1.f - ay, bx0 = 1.f - ax;
    bool vy0 = (unsigned)y0 < 128u, vy1 = (unsigned)y1i < 128u;
    bool vx0 = (unsigned)x0 < 128u, vx1 = (unsigned)x1i < 128u;
    w00 = (vy0 && vx0) ? by0 * bx0 : 0.f;
    w01 = (vy0 && vx1) ? by0 * ax : 0.f;
    w10 = (vy1 && vx0) ? ay * bx0 : 0.f;
    w11 = (vy1 && vx1) ? ay * ax : 0.f;
    int iy0 = min(max(y0, 0), 127), iy1 = min(max(y1i, 0), 127);
    int ix0 = min(max(x0, 0), 127), ix1 = min(max(x1i, 0), 127);
    a00 = (iy0 * WIDTH + ix0) << 7;
    a01 = (iy0 * WIDTH + ix1) << 7;
    a10 = (iy1 * WIDTH + ix0) << 7;
    a11 = (iy1 * WIDTH + ix1) << 7;
  }
  float e00 = 0.f, e01 = 0.f, e10 = 0.f, e11 = 0.f;
  int b00 = 0, b01 = 0, b10 = 0, b11 = 0;
  if (wave < 4) {  // tap 8
    int px = px0 + lane;
    int y = px >> 7, xc = px & 127;
    float dy = offsL[lane * 18 + 16];
    float dx = offsL[lane * 18 + 17];
    float py = (float)(y + 1) + dy;
    float pxx = (float)(xc + 1) + dx;
    float y0f = floorf(py), x0f = floorf(pxx);
    float ay = py - y0f, ax = pxx - x0f;
    int y0 = (int)y0f, x0 = (int)x0f;
    int y1i = y0 + 1, x1i = x0 + 1;
    float by0 = 1.f - ay, bx0 = 1.f - ax;
    bool vy0 = (unsigned)y0 < 128u, vy1 = (unsigned)y1i < 128u;
    bool vx0 = (unsigned)x0 < 128u, vx1 = (unsigned)x1i < 128u;
    e00 = (vy0 && vx0) ? by0 * bx0 : 0.f;
    e01 = (vy0 && vx1) ? by0 * ax : 0.f;
    e10 = (vy1 && vx0) ? ay * bx0 : 0.f;
    e11 = (vy1 && vx1) ? ay * ax : 0.f;
    int iy0 = min(max(y0, 0), 127), iy1 = min(max(y1i, 0), 127);
    int ix0 = min(max(x0, 0), 127), ix1 = min(max(x1i, 0), 127);
    b00 = (iy0 * WIDTH + ix0) << 7;
    b01 = (iy0 * WIDTH + ix1) << 7;
    b10 = (iy1 * WIDTH + ix0) << 7;
    b11 = (iy1 * WIDTH + ix1) << 7;
  }
  __syncthreads();  // all offsL reads complete before P3 overwrites A

  // ---- P3/P4: bilinear build + GEMM1, two channel halves; + residual, A2 ----
  int n1 = wave & 3;
  int mh = wave >> 2;
  f32x4 acc0 = {0.f, 0.f, 0.f, 0.f};
  f32x4 acc1 = {0.f, 0.f, 0.f, 0.f};
  int kcbA = (wave * 4 + ch4) * 1040;
  int kcb8 = (32 + ch4) * 1040;
  for (int h = 0; h < 2; ++h) {
    int co = (h << 6) + (ch4 << 4);
#pragma unroll
    for (int g = 0; g < 4; ++g) {
      int src = (g << 4) + q16;
      float j0 = __shfl(w00, src), j1 = __shfl(w01, src);
      float j2 = __shfl(w10, src), j3 = __shfl(w11, src);
      int c0 = __shfl(a00, src), c1 = __shfl(a01, src);
      int c2 = __shfl(a10, src), c3 = __shfl(a11, src);
      uint4 v0 = *(const uint4*)(xbt + c0 + co);
      uint4 v1 = *(const uint4*)(xbt + c1 + co);
      uint4 v2 = *(const uint4*)(xbt + c2 + co);
      uint4 v3 = *(const uint4*)(xbt + c3 + co);
      float r[8];
      r[0] = j0 * bflo(v0.x) + j1 * bflo(v1.x) + j2 * bflo(v2.x) + j3 * bflo(v3.x);
      r[1] = j0 * bfhi(v0.x) + j1 * bfhi(v1.x) + j2 * bfhi(v2.x) + j3 * bfhi(v3.x);
      r[2] = j0 * bflo(v0.y) + j1 * bflo(v1.y) + j2 * bflo(v2.y) + j3 * bflo(v3.y);
      r[3] = j0 * bfhi(v0.y) + j1 * bfhi(v1.y) + j2 * bfhi(v2.y) + j3 * bfhi(v3.y);
      r[4] = j0 * bflo(v0.z) + j1 * bflo(v1.z) + j2 * bflo(v2.z) + j3 * bflo(v3.z);
      r[5] = j0 * bfhi(v0.z) + j1 * bfhi(v1.z) + j2 * bfhi(v2.z) + j3 * bfhi(v3.z);
      r[6] = j0 * bflo(v0.w) + j1 * bflo(v1.w) + j2 * bflo(v2.w) + j3 * bflo(v3.w);
      r[7] = j0 * bfhi(v0.w) + j1 * bfhi(v1.w) + j2 * bfhi(v2.w) + j3 * bfhi(v3.w);
      uint4 ov;
      asm("v_cvt_pk_bf16_f32 %0, %1, %2" : "=v"(ov.x) : "v"(r[0]), "v"(r[1]));
      asm("v_cvt_pk_bf16_f32 %0, %1, %2" : "=v"(ov.y) : "v"(r[2]), "v"(r[3]));
      asm("v_cvt_pk_bf16_f32 %0, %1, %2" : "=v"(ov.z) : "v"(r[4]), "v"(r[5]));
      asm("v_cvt_pk_bf16_f32 %0, %1, %2" : "=v"(ov.w) : "v"(r[6]), "v"(r[7]));
      *(uint4*)((char*)A + kcbA + src * 16) = ov;
    }
    if (wave < 4) {  // tap 8: one px-group per wave
      int src = (wave << 4) + q16;
      float j0 = __shfl(e00, src), j1 = __shfl(e01, src);
      float j2 = __shfl(e10, src), j3 = __shfl(e11, src);
      int c0 = __shfl(b00, src), c1 = __shfl(b01, src);
      int c2 = __shfl(b10, src), c3 = __shfl(b11, src);
      uint4 v0 = *(const uint4*)(xbt + c0 + co);
      uint4 v1 = *(const uint4*)(xbt + c1 + co);
      uint4 v2 = *(const uint4*)(xbt + c2 + co);
      uint4 v3 = *(const uint4*)(xbt + c3 + co);
      float r[8];
      r[0] = j0 * bflo(v0.x) + j1 * bflo(v1.x) + j2 * bflo(v2.x) + j3 * bflo(v3.x);
      r[1] = j0 * bfhi(v0.x) + j1 * bfhi(v1.x) + j2 * bfhi(v2.x) + j3 * bfhi(v3.x);
      r[2] = j0 * bflo(v0.y) + j1 * bflo(v1.y) + j2 * bflo(v2.y) + j3 * bflo(v3.y);
      r[3] = j0 * bfhi(v0.y) + j1 * bfhi(v1.y) + j2 * bfhi(v2.y) + j3 * bfhi(v3.y);
      r[4] = j0 * bflo(v0.z) + j1 * bflo(v1.z) + j2 * bflo(v2.z) + j3 * bflo(v3.z);
      r[5] = j0 * bfhi(v0.z) + j1 * bfhi(v1.z) + j2 * bfhi(v2.z) + j3 * bfhi(v3.z);
      r[6] = j0 * bflo(v0.w) + j1 * bflo(v1.w) + j2 * bflo(v2.w) + j3 * bflo(v3.w);
      r[7] = j0 * bfhi(v0.w) + j1 * bfhi(v1.w) + j2 * bfhi(v2.w) + j3 * bfhi(v3.w);
      uint4 ov;
      asm("v_cvt_pk_bf16_f32 %0, %1, %2" : "=v"(ov.x) : "v"(r[0]), "v"(r[1]));
      asm("v_cvt_pk_bf16_f32 %0, %1, %2" : "=v"(ov.y) : "v"(r[2]), "v"(r[3]));
      asm("v_cvt_pk_bf16_f32 %0, %1, %2" : "=v"(ov.z) : "v"(r[4]), "v"(r[5]));
      asm("v_cvt_pk_bf16_f32 %0, %1, %2" : "=v"(ov.w) : "v"(r[6]), "v"(r[7]));
      *(uint4*)((char*)A + kcb8 + src * 16) = ov;
    }
    __syncthreads();
    {
      int r0r = mh * 32 + (lane & 15);
      const bf16x8* wp = (const bf16x8*)wBf;
      __builtin_amdgcn_s_setprio(1);
#pragma unroll
      for (int tap = 0; tap < 9; ++tap) {
        bf16x8 bk = wp[((2 * tap + h) * 4 + n1) * 64 + lane];
        int kc = tap * 4 + kq;
        bf16x8 a0 = *(const bf16x8*)((const char*)A + (kc * 65 + r0r) * 16);
        bf16x8 a1 = *(const bf16x8*)((const char*)A + (kc * 65 + r0r + 16) * 16);
        acc0 = __builtin_amdgcn_mfma_f32_16x16x32_bf16(a0, bk, acc0, 0, 0, 0);
        acc1 = __builtin_amdgcn_mfma_f32_16x16x32_bf16(a1, bk, acc1, 0, 0, 0);
      }
      __builtin_amdgcn_s_setprio(0);
    }
    __syncthreads();
  }
  // residual (bf16 unpack) + A2 write
  {
    int c = n1 * 16 + (lane & 15);
    int pb = px0 + mh * 32 + ((lane >> 4) << 2);
#pragma unroll
    for (int r = 0; r < 4; r++) {
      acc0[r] += __uint_as_float((unsigned int)xtf[(size_t)(pb + r) * 64 + c] << 16);
      acc1[r] += __uint_as_float((unsigned int)xtf[(size_t)(pb + 16 + r) * 64 + c] << 16);
    }
    char* base = (char*)A + (c >> 3) * 1040 + (c & 7) * 2;
    int pxr = mh * 32 + ((lane >> 4) << 2);
#pragma unroll
    for (int r = 0; r < 4; r++) {
      *(unsigned short*)(base + (size_t)(pxr + r) * 16) = f2bf(acc0[r]);
      *(unsigned short*)(base + (size_t)(pxr + 16 + r) * 16) = f2bf(acc1[r]);
    }
  }
  __syncthreads();

  // ---- P6: GEMM2 (M=64, N=256, K=64), two n-half passes (16 acc regs each) ----
  unsigned short* tb = t3 + (size_t)bb * 256 * HW + px0;
  int mtq = (wave >> 2) * 32 + ((lane >> 4) << 2);
#pragma unroll
  for (int half = 0; half < 2; half++) {
    f32x4 cA[2], cB[2];
#pragma unroll
    for (int ni = 0; ni < 2; ni++) {
      cA[ni] = (f32x4){0.f, 0.f, 0.f, 0.f};
      cB[ni] = (f32x4){0.f, 0.f, 0.f, 0.f};
    }
    {
      int mt0 = (wave >> 2) * 2;
      const bf16x8* wp2 = (const bf16x8*)w3Bf;
      __builtin_amdgcn_s_setprio(1);
#pragma unroll
      for (int kt = 0; kt < 2; kt++) {
        int kc = kt * 4 + kq;
        bf16x8 aA = *(const bf16x8*)((const char*)A + (size_t)(kc * 65 + mt0 * 16 + (lane & 15)) * 16);
        bf16x8 aB = *(const bf16x8*)((const char*)A + (size_t)(kc * 65 + (mt0 + 1) * 16 + (lane & 15)) * 16);
#pragma unroll
        for (int ni = 0; ni < 2; ni++) {
          int ng = n1 * 4 + half * 2 + ni;
          bf16x8 bk = wp2[(kt * 16 + ng) * 64 + lane];
          cA[ni] = __builtin_amdgcn_mfma_f32_16x16x32_bf16(aA, bk, cA[ni], 0, 0, 0);
          cB[ni] = __builtin_amdgcn_mfma_f32_16x16x32_bf16(aB, bk, cB[ni], 0, 0, 0);
        }
      }
      __builtin_amdgcn_s_setprio(0);
    }
#pragma unroll
    for (int ni = 0; ni < 2; ni++) {
      int niA = half * 2 + ni;
      float s = 0.f, qq = 0.f;
#pragma unroll
      for (int r = 0; r < 4; r++) {
        float v0 = cA[ni][r], v1 = cB[ni][r];
        s += v0 + v1; qq += v0 * v0 + v1 * v1;
      }
      s += __shfl_down(s, 32); qq += __shfl_down(qq, 32);
      s += __shfl_down(s, 16); qq += __shfl_down(qq, 16);
      s += __shfl_down(s, 4);  qq += __shfl_down(qq, 4);
      s += __shfl_down(s, 2);  qq += __shfl_down(qq, 2);
      s += __shfl_down(s, 1);  qq += __shfl_down(qq, 1);
      if (lane == 0 || lane == 8) {
        int g = (n1 * 4 + niA) * 2 + (lane >> 3);
        int slot = ((bb * 32 + g) * 256 + tileid) * 2 + (wave >> 2);
        ps2[slot * 2] = s;
        ps2[slot * 2 + 1] = qq;
      }
      int o = (n1 * 4 + niA) * 16 + (lane & 15);
      unsigned short* p0 = tb + (size_t)o * HW + mtq;
      unsigned int u0, u1, u2, u3;
      asm("v_cvt_pk_bf16_f32 %0, %1, %2" : "=v"(u0) : "v"(cA[ni][0]), "v"(cA[ni][1]));
      asm("v_cvt_pk_bf16_f32 %0, %1, %2" : "=v"(u1) : "v"(cA[ni][2]), "v"(cA[ni][3]));
      asm("v_cvt_pk_bf16_f32 %0, %1, %2" : "=v"(u2) : "v"(cB[ni][0]), "v"(cB[ni][1]));
      asm("v_cvt_pk_bf16_f32 %0, %1, %2" : "=v"(u3) : "v"(cB[ni][2]), "v"(cB[ni][3]));
      *(uint2*)p0 = make_uint2(u0, u1);
      *(uint2*)(p0 + 16) = make_uint2(u2, u3);
    }
  }
}

// ---- K8: out = relu(gn2(t3_bf16)) + x ----
__global__ __launch_bounds__(256) void k_final(const unsigned short* __restrict__ t3, const float* __restrict__ x,
                                               const float* __restrict__ mrs, const float* __restrict__ g3,
                                               const float* __restrict__ b3, float* __restrict__ out) {
  int i4 = blockIdx.x * 256 + threadIdx.x;
  int b = i4 >> 20;
  int c = (i4 >> 12) & 255;
  int g = c >> 3;
  float mu = mrs[b * 32 + g], rs = mrs[128 + b * 32 + g];
  float ga = g3[c] * rs, be = b3[c] - mu * ga;
  uint2 tv = ((const uint2*)t3)[i4];
  float t0 = bflo(tv.x);
  float t1 = bfhi(tv.x);
  float t2 = bflo(tv.y);
  float t3v = bfhi(tv.y);
  float4 xv = ((const float4*)x)[i4];
  float4 r;
  r.x = fmaxf(t0 * ga + be, 0.f) + xv.x;
  r.y = fmaxf(t1 * ga + be, 0.f) + xv.y;
  r.z = fmaxf(t2 * ga + be, 0.f) + xv.z;
  r.w = fmaxf(t3v * ga + be, 0.f) + xv.w;
  ((float4*)out)[i4] = r;
}

extern "C" void kernel_launch(void* const* d_in, const int* in_sizes, int n_in,
                              void* d_out, int out_size, void* d_ws, size_t ws_size,
                              hipStream_t stream) {
  const float* x    = (const float*)d_in[0];
  const float* w1   = (const float*)d_in[1];
  const float* g1   = (const float*)d_in[2];
  const float* b1   = (const float*)d_in[3];
  const float* woff = (const float*)d_in[4];
  const float* wdef = (const float*)d_in[5];
  const float* w3   = (const float*)d_in[6];
  const float* g3   = (const float*)d_in[7];
  const float* b3   = (const float*)d_in[8];
  float* ws = (float*)d_ws;

  unsigned short* xdT = (unsigned short*)ws;               // 4,194,304 ush = 2,097,152 fl
  unsigned short* t3  = (unsigned short*)(ws + 2097152);   // 16,777,216 ush = 8,388,608 fl
  float* base = ws + 2097152 + 8388608;
  float* mrs1 = base;                     // 256
  float* mrs2 = mrs1 + 256;               // 256
  unsigned short* wA1f  = (unsigned short*)(mrs2 + 256);                        // 8,192 fl
  unsigned short* wBf   = (unsigned short*)(mrs2 + 256 + 8192);                 // 18,432 fl
  unsigned short* wofBf = (unsigned short*)(mrs2 + 256 + 8192 + 18432);         // 9,216 fl
  unsigned short* w3Bf  = (unsigned short*)(mrs2 + 256 + 8192 + 18432 + 9216);  // 16,384 fl
  float* ps   = mrs2 + 256 + 8192 + 18432 + 9216 + 16384;  // 65,536
  float* ps2  = ps + 65536;               // 131,072
  float* out  = (float*)d_out;

  hipLaunchKernelGGL(k_prep, dim3(144), dim3(256), 0, stream, w1, w3, wdef, woff, wA1f, wBf, wofBf, w3Bf);
  hipLaunchKernelGGL(k_conv1m, dim3(1024), dim3(256), 0, stream, x, wA1f, xdT, ps);
  hipLaunchKernelGGL(k_gnfin_p, dim3(128), dim3(256), 0, stream, ps, mrs1, 256, (float)(2 * HW));
  hipLaunchKernelGGL(k_gnapply_bf, dim3(2048), dim3(256), 0, stream, xdT, mrs1, g1, b1);
  hipLaunchKernelGGL(k_mega, dim3(1024), dim3(512), 0, stream, xdT, wofBf, wBf, w3Bf, t3, ps2);
  hipLaunchKernelGGL(k_gnfin_p, dim3(128), dim3(256), 0, stream, ps2, mrs2, 512, 131072.f);
  hipLaunchKernelGGL(k_final, dim3(16384), dim3(256), 0, stream, t3, x, mrs2, g3, b3, out);
}

// Round 20
// 100.467 us; speedup vs baseline: 1.5333x; 1.0318x over previous
//
#include <hip/hip_runtime.h>

// deformMP: B=4, Cc=256, ci=64, H=W=128, GN groups=32, eps=1e-5
// ws: xdTbf[2.10M fl-equiv NHWC bf16] t3bf[8.39M] mrs1/2 wA1f wBf wofBf w3Bf ps ps2
// k_mega v8 = v7 + tap-8 geometry moved to dedicated LDS (gBw/gBa, 2KB; computed
// once by wave 0) -> kills the 8-reg live range that was spilling at the 64-reg cap.

#define HW 16384
#define WIDTH 128

typedef __attribute__((ext_vector_type(8))) short bf16x8;
typedef __attribute__((ext_vector_type(4))) float f32x4;

__device__ __forceinline__ unsigned short f2bf(float f) {
  unsigned int u = __float_as_uint(f);
  u = (u + 0x7fffu + ((u >> 16) & 1u)) >> 16;  // RNE
  return (unsigned short)u;
}
__device__ __forceinline__ float bflo(unsigned int u) { return __uint_as_float(u << 16); }
__device__ __forceinline__ float bfhi(unsigned int u) { return __uint_as_float(u & 0xffff0000u); }

// ---- K0: weight repack (unchanged) ----
__global__ __launch_bounds__(256) void k_prep(const float* __restrict__ w1, const float* __restrict__ w3,
                                              const float* __restrict__ wdef, const float* __restrict__ woff,
                                              unsigned short* __restrict__ wA1f,
                                              unsigned short* __restrict__ wBf,
                                              unsigned short* __restrict__ wofBf,
                                              unsigned short* __restrict__ w3Bf) {
  int i = blockIdx.x * 256 + threadIdx.x;
  if (i < 16384) {
    int j = i & 7;
    int lane = (i >> 3) & 63;
    int m = (i >> 9) & 3;
    int kt = i >> 11;
    int o = (m << 4) + (lane & 15);
    int c = kt * 32 + ((lane >> 4) << 3) + j;
    wA1f[i] = f2bf(w1[(size_t)o * 256 + c]);
  }
  if (i < 36864) {
    int j = i & 7;
    int lane = (i >> 3) & 63;
    int n = (i >> 9) & 3;
    int kt = i >> 11;
    int kk = kt * 32 + ((lane >> 4) << 3) + j;
    int tap = kk >> 6, c = kk & 63;
    int o = (n << 4) + (lane & 15);
    wBf[i] = f2bf(wdef[(size_t)o * 576 + c * 9 + tap]);
  }
  if (i < 18432) {
    int j = i & 7;
    int lane = (i >> 3) & 63;
    int n = (i >> 9) & 1;
    int kt = i >> 10;
    int kk = kt * 32 + ((lane >> 4) << 3) + j;
    int tap = kk >> 6, c = kk & 63;
    int o = (n << 4) + (lane & 15);
    wofBf[i] = (o < 18) ? f2bf(woff[((size_t)(o * 64 + c)) * 9 + tap]) : (unsigned short)0;
  }
  if (i < 32768) {
    int j = i & 7;
    int lane = (i >> 3) & 63;
    int n = (i >> 9) & 15;
    int kt = i >> 13;
    int c = kt * 32 + ((lane >> 4) << 3) + j;
    int o = (n << 4) + (lane & 15);
    w3Bf[i] = f2bf(w3[(size_t)o * 64 + c]);
  }
}

// ---- K1: conv1x1 256->64 via bf16 MFMA, double-buffered staging, bf16 NHWC + GN1 partials ----
__global__ __launch_bounds__(256) void k_conv1m(const float* __restrict__ x,
                                                const unsigned short* __restrict__ wA1f,
                                                unsigned short* __restrict__ xdT, float* __restrict__ ps) {
  __shared__ unsigned short xs[2][64][72];
  __shared__ float lds_s[4][32], lds_ss[4][32];
  int tid = threadIdx.x;
  int wave = tid >> 6, lane = tid & 63;
  int b = blockIdx.x >> 8;
  int chunk = blockIdx.x & 255;
  int px0 = chunk << 6;
  int pxl = lane & 15, q = lane >> 4;
  const float* xb = x + (size_t)b * 256 * HW + px0;
  const bf16x8* wAp = (const bf16x8*)wA1f;
  int sc = tid >> 4;
  int sq = tid & 15;
  f32x4 acc[4];
#pragma unroll
  for (int m = 0; m < 4; m++) acc[m] = (f32x4){0.f, 0.f, 0.f, 0.f};

  float4 vr[4];
#pragma unroll
  for (int r = 0; r < 4; r++)
    vr[r] = *(const float4*)(xb + (size_t)(r * 16 + sc) * HW + sq * 4);
#pragma unroll
  for (int r = 0; r < 4; r++) {
    int c = r * 16 + sc;
    xs[0][sq * 4 + 0][c] = f2bf(vr[r].x);
    xs[0][sq * 4 + 1][c] = f2bf(vr[r].y);
    xs[0][sq * 4 + 2][c] = f2bf(vr[r].z);
    xs[0][sq * 4 + 3][c] = f2bf(vr[r].w);
  }
  __syncthreads();

  for (int cb = 0; cb < 4; cb++) {
    int cur = cb & 1;
    if (cb < 3) {
#pragma unroll
      for (int r = 0; r < 4; r++)
        vr[r] = *(const float4*)(xb + (size_t)((cb + 1) * 64 + r * 16 + sc) * HW + sq * 4);
    }
#pragma unroll
    for (int kt = 0; kt < 2; kt++) {
      bf16x8 bfrag = *(const bf16x8*)&xs[cur][wave * 16 + pxl][kt * 32 + q * 8];
      int ktG = cb * 2 + kt;
#pragma unroll
      for (int m = 0; m < 4; m++) {
        bf16x8 af = wAp[(ktG * 4 + m) * 64 + lane];
        acc[m] = __builtin_amdgcn_mfma_f32_16x16x32_bf16(af, bfrag, acc[m], 0, 0, 0);
      }
    }
    if (cb < 3) {
#pragma unroll
      for (int r = 0; r < 4; r++) {
        int c = r * 16 + sc;
        xs[cur ^ 1][sq * 4 + 0][c] = f2bf(vr[r].x);
        xs[cur ^ 1][sq * 4 + 1][c] = f2bf(vr[r].y);
        xs[cur ^ 1][sq * 4 + 2][c] = f2bf(vr[r].z);
        xs[cur ^ 1][sq * 4 + 3][c] = f2bf(vr[r].w);
      }
    }
    __syncthreads();
  }
  unsigned short* xo = xdT + ((size_t)b * HW + px0 + wave * 16 + pxl) * 64 + (q << 2);
#pragma unroll
  for (int m = 0; m < 4; m++) {
    unsigned int u0, u1;
    asm("v_cvt_pk_bf16_f32 %0, %1, %2" : "=v"(u0) : "v"(acc[m][0]), "v"(acc[m][1]));
    asm("v_cvt_pk_bf16_f32 %0, %1, %2" : "=v"(u1) : "v"(acc[m][2]), "v"(acc[m][3]));
    *(uint2*)(xo + m * 16) = make_uint2(u0, u1);
  }
  float s[8], sq2[8];
#pragma unroll
  for (int m = 0; m < 4; m++)
#pragma unroll
    for (int h = 0; h < 2; h++) {
      float a = acc[m][2 * h] + acc[m][2 * h + 1];
      float qq = acc[m][2 * h] * acc[m][2 * h] + acc[m][2 * h + 1] * acc[m][2 * h + 1];
      s[m * 2 + h] = a; sq2[m * 2 + h] = qq;
    }
#pragma unroll
  for (int i = 0; i < 8; i++) {
#pragma unroll
    for (int off = 8; off; off >>= 1) {
      s[i] += __shfl_down(s[i], off, 16);
      sq2[i] += __shfl_down(sq2[i], off, 16);
    }
  }
  if (pxl == 0) {
#pragma unroll
    for (int i = 0; i < 8; i++) {
      int m = i >> 1, h = i & 1;
      int g = m * 8 + q * 2 + h;
      lds_s[wave][g] = s[i];
      lds_ss[wave][g] = sq2[i];
    }
  }
  __syncthreads();
  if (tid < 32) {
    float S = lds_s[0][tid] + lds_s[1][tid] + lds_s[2][tid] + lds_s[3][tid];
    float SS = lds_ss[0][tid] + lds_ss[1][tid] + lds_ss[2][tid] + lds_ss[3][tid];
    int bg = b * 32 + tid;
    ps[(bg * 256 + chunk) * 2] = S;
    ps[(bg * 256 + chunk) * 2 + 1] = SS;
  }
}

// ---- K2: finalize GN stats, block-parallel ----
__global__ __launch_bounds__(256) void k_gnfin_p(const float* __restrict__ ps, float* __restrict__ mrs,
                                                 int S, float n) {
  int bg = blockIdx.x;
  float s = 0.f, ss = 0.f;
  for (int i = threadIdx.x; i < S; i += 256) { s += ps[(bg * S + i) * 2]; ss += ps[(bg * S + i) * 2 + 1]; }
#pragma unroll
  for (int off = 32; off; off >>= 1) { s += __shfl_down(s, off); ss += __shfl_down(ss, off); }
  __shared__ float ls[4], lss[4];
  int wv = threadIdx.x >> 6;
  if ((threadIdx.x & 63) == 0) { ls[wv] = s; lss[wv] = ss; }
  __syncthreads();
  if (threadIdx.x == 0) {
    float Sa = ls[0] + ls[1] + ls[2] + ls[3];
    float SSa = lss[0] + lss[1] + lss[2] + lss[3];
    float mu = Sa / n;
    float var = SSa / n - mu * mu;
    mrs[bg] = mu;
    mrs[128 + bg] = rsqrtf(var + 1e-5f);
  }
}

// ---- K3: GN1 + ReLU in place on bf16 xdT ----
__global__ __launch_bounds__(256) void k_gnapply_bf(unsigned short* __restrict__ xdT,
                                                    const float* __restrict__ mrs,
                                                    const float* __restrict__ g1, const float* __restrict__ b1) {
  int i = blockIdx.x * 256 + threadIdx.x;
  int b = i >> 17;
  int ck = i & 7;
  int c0 = ck << 3;
  uint4 v = ((const uint4*)xdT)[i];
  float ga[8], be[8];
#pragma unroll
  for (int j = 0; j < 8; j += 2) {
    int g = (c0 + j) >> 1;
    float mu = mrs[b * 32 + g], rs = mrs[128 + b * 32 + g];
    ga[j] = g1[c0 + j] * rs;     be[j] = b1[c0 + j] - mu * ga[j];
    ga[j + 1] = g1[c0 + j + 1] * rs; be[j + 1] = b1[c0 + j + 1] - mu * ga[j + 1];
  }
  float r[8];
  r[0] = fmaxf(bflo(v.x) * ga[0] + be[0], 0.f);
  r[1] = fmaxf(bfhi(v.x) * ga[1] + be[1], 0.f);
  r[2] = fmaxf(bflo(v.y) * ga[2] + be[2], 0.f);
  r[3] = fmaxf(bfhi(v.y) * ga[3] + be[3], 0.f);
  r[4] = fmaxf(bflo(v.z) * ga[4] + be[4], 0.f);
  r[5] = fmaxf(bfhi(v.z) * ga[5] + be[5], 0.f);
  r[6] = fmaxf(bflo(v.w) * ga[6] + be[6], 0.f);
  r[7] = fmaxf(bfhi(v.w) * ga[7] + be[7], 0.f);
  uint4 o;
  asm("v_cvt_pk_bf16_f32 %0, %1, %2" : "=v"(o.x) : "v"(r[0]), "v"(r[1]));
  asm("v_cvt_pk_bf16_f32 %0, %1, %2" : "=v"(o.y) : "v"(r[2]), "v"(r[3]));
  asm("v_cvt_pk_bf16_f32 %0, %1, %2" : "=v"(o.z) : "v"(r[4]), "v"(r[5]));
  asm("v_cvt_pk_bf16_f32 %0, %1, %2" : "=v"(o.w) : "v"(r[6]), "v"(r[7]));
  ((uint4*)xdT)[i] = o;
}

// ---- K5: MEGA v8 — v7 + tap-8 geometry in dedicated LDS (no spill) ----
__global__ __launch_bounds__(512, 8) void k_mega(const unsigned short* __restrict__ xdT,
                                                 const unsigned short* __restrict__ wofBf,
                                                 const unsigned short* __restrict__ wBf,
                                                 const unsigned short* __restrict__ w3Bf,
                                                 unsigned short* __restrict__ t3,
                                                 float* __restrict__ ps2) {
  __shared__ unsigned short A[36 * 65 * 8];  // 37,440 B; offsL aliases bytes [0,4608)
  __shared__ float gBw[64][4];               // 1,024 B: tap-8 bilinear weights
  __shared__ int gBa[64][4];                 // 1,024 B: tap-8 corner byte addrs
  float* offsL = (float*)A;
  int tid = threadIdx.x;
  int bb = blockIdx.x & 3;          // batch-L2 swizzle
  int tileid = blockIdx.x >> 2;
  int px0 = tileid << 6;
  const unsigned short* xtf = xdT + (size_t)bb * 64 * HW;  // bf16 NHWC (normalized)
  const char* xbt = (const char*)xtf;
  int wave = tid >> 6;  // 0..7
  int lane = tid & 63;
  int q16 = lane >> 2;
  int ch4 = lane & 3;
  int kq = lane >> 4;

  // ---- P0/P1: fixed-tap im2col build + off-GEMM; taps = wave (+ tap 8 via waves 0-3) ----
  f32x4 aoff = {0.f, 0.f, 0.f, 0.f};
  {
    int kyA = wave / 3 - 1, kxA = wave % 3 - 1;
    int kcbA = (wave * 4 + ch4) * 1040;
    int kcb8 = (32 + ch4) * 1040;
    int n2 = wave & 1;
    int mh1 = wave >> 1;
    int r1 = mh1 * 16 + (lane & 15);
    for (int h = 0; h < 2; ++h) {
      int co = (h << 6) + (ch4 << 4);
#pragma unroll
      for (int g = 0; g < 4; ++g) {
        int src = (g << 4) + q16;
        int px = px0 + src;
        int sy = (px >> 7) + kyA;
        int sx = (px & 127) + kxA;
        bool valid = ((unsigned)sy < 128u) && ((unsigned)sx < 128u);
        uint4 v = make_uint4(0u, 0u, 0u, 0u);
        if (valid) v = *(const uint4*)(xbt + (((sy << 7) + sx) << 7) + co);
        *(uint4*)((char*)A + kcbA + src * 16) = v;
      }
      if (wave < 4) {  // tap 8 (ky=1,kx=1): one px-group per wave
        int src = (wave << 4) + q16;
        int px = px0 + src;
        int sy = (px >> 7) + 1;
        int sx = (px & 127) + 1;
        bool valid = ((unsigned)sy < 128u) && ((unsigned)sx < 128u);
        uint4 v = make_uint4(0u, 0u, 0u, 0u);
        if (valid) v = *(const uint4*)(xbt + (((sy << 7) + sx) << 7) + co);
        *(uint4*)((char*)A + kcb8 + src * 16) = v;
      }
      __syncthreads();
      {
        const bf16x8* wp = (const bf16x8*)wofBf;
        __builtin_amdgcn_s_setprio(1);
#pragma unroll
        for (int tap = 0; tap < 9; ++tap) {
          bf16x8 bk = wp[((2 * tap + h) * 2 + n2) * 64 + lane];
          bf16x8 a0 = *(const bf16x8*)((const char*)A + ((tap * 4 + kq) * 65 + r1) * 16);
          aoff = __builtin_amdgcn_mfma_f32_16x16x32_bf16(a0, bk, aoff, 0, 0, 0);
        }
        __builtin_amdgcn_s_setprio(0);
      }
      __syncthreads();
    }
    // offsL write (aliases A; im2col content now dead)
    {
      int o = n2 * 16 + (lane & 15);
      if (o < 18) {
        int prow = mh1 * 16 + ((lane >> 4) << 2);
#pragma unroll
        for (int r = 0; r < 4; r++) offsL[(prow + r) * 18 + o] = aoff[r];
      }
    }
  }
  __syncthreads();  // offsL ready

  // ---- P2: geometry. geomA: (pxl=lane, tap=wave) in regs. tap-8: wave 0 -> gBw/gBa LDS ----
  float w00, w01, w10, w11;
  int a00, a01, a10, a11;
  {
    int px = px0 + lane;
    int y = px >> 7, xc = px & 127;
    float dy = offsL[lane * 18 + 2 * wave];
    float dx = offsL[lane * 18 + 2 * wave + 1];
    float py = (float)(y + wave / 3 - 1) + dy;
    float pxx = (float)(xc + wave % 3 - 1) + dx;
    float y0f = floorf(py), x0f = floorf(pxx);
    float ay = py - y0f, ax = pxx - x0f;
    int y0 = (int)y0f, x0 = (int)x0f;
    int y1i = y0 + 1, x1i = x0 + 1;
    float by0 = 1.f - ay, bx0 = 1.f - ax;
    bool vy0 = (unsigned)y0 < 128u, vy1 = (unsigned)y1i < 128u;
    bool vx0 = (unsigned)x0 < 128u, vx1 = (unsigned)x1i < 128u;
    w00 = (vy0 && vx0) ? by0 * bx0 : 0.f;
    w01 = (vy0 && vx1) ? by0 * ax : 0.f;
    w10 = (vy1 && vx0) ? ay * bx0 : 0.f;
    w11 = (vy1 && vx1) ? ay * ax : 0.f;
    int iy0 = min(max(y0, 0), 127), iy1 = min(max(y1i, 0), 127);
    int ix0 = min(max(x0, 0), 127), ix1 = min(max(x1i, 0), 127);
    a00 = (iy0 * WIDTH + ix0) << 7;
    a01 = (iy0 * WIDTH + ix1) << 7;
    a10 = (iy1 * WIDTH + ix0) << 7;
    a11 = (iy1 * WIDTH + ix1) << 7;
  }
  if (wave == 0) {  // tap 8 geometry -> LDS (computed once)
    int px = px0 + lane;
    int y = px >> 7, xc = px & 127;
    float dy = offsL[lane * 18 + 16];
    float dx = offsL[lane * 18 + 17];
    float py = (float)(y + 1) + dy;
    float pxx = (float)(xc + 1) + dx;
    float y0f = floorf(py), x0f = floorf(pxx);
    float ay = py - y0f, ax = pxx - x0f;
    int y0 = (int)y0f, x0 = (int)x0f;
    int y1i = y0 + 1, x1i = x0 + 1;
    float by0 = 1.f - ay, bx0 = 1.f - ax;
    bool vy0 = (unsigned)y0 < 128u, vy1 = (unsigned)y1i < 128u;
    bool vx0 = (unsigned)x0 < 128u, vx1 = (unsigned)x1i < 128u;
    gBw[lane][0] = (vy0 && vx0) ? by0 * bx0 : 0.f;
    gBw[lane][1] = (vy0 && vx1) ? by0 * ax : 0.f;
    gBw[lane][2] = (vy1 && vx0) ? ay * bx0 : 0.f;
    gBw[lane][3] = (vy1 && vx1) ? ay * ax : 0.f;
    int iy0 = min(max(y0, 0), 127), iy1 = min(max(y1i, 0), 127);
    int ix0 = min(max(x0, 0), 127), ix1 = min(max(x1i, 0), 127);
    gBa[lane][0] = (iy0 * WIDTH + ix0) << 7;
    gBa[lane][1] = (iy0 * WIDTH + ix1) << 7;
    gBa[lane][2] = (iy1 * WIDTH + ix0) << 7;
    gBa[lane][3] = (iy1 * WIDTH + ix1) << 7;
  }
  __syncthreads();  // offsL reads + gB writes complete before P3 overwrites A

  // ---- P3/P4: bilinear build + GEMM1, two channel halves; + residual, A2 ----
  int n1 = wave & 3;
  int mh = wave >> 2;
  f32x4 acc0 = {0.f, 0.f, 0.f, 0.f};
  f32x4 acc1 = {0.f, 0.f, 0.f, 0.f};
  int kcbA = (wave * 4 + ch4) * 1040;
  int kcb8 = (32 + ch4) * 1040;
  for (int h = 0; h < 2; ++h) {
    int co = (h << 6) + (ch4 << 4);
#pragma unroll
    for (int g = 0; g < 4; ++g) {
      int src = (g << 4) + q16;
      float j0 = __shfl(w00, src), j1 = __shfl(w01, src);
      float j2 = __shfl(w10, src), j3 = __shfl(w11, src);
      int c0 = __shfl(a00, src), c1 = __shfl(a01, src);
      int c2 = __shfl(a10, src), c3 = __shfl(a11, src);
      uint4 v0 = *(const uint4*)(xbt + c0 + co);
      uint4 v1 = *(const uint4*)(xbt + c1 + co);
      uint4 v2 = *(const uint4*)(xbt + c2 + co);
      uint4 v3 = *(const uint4*)(xbt + c3 + co);
      float r[8];
      r[0] = j0 * bflo(v0.x) + j1 * bflo(v1.x) + j2 * bflo(v2.x) + j3 * bflo(v3.x);
      r[1] = j0 * bfhi(v0.x) + j1 * bfhi(v1.x) + j2 * bfhi(v2.x) + j3 * bfhi(v3.x);
      r[2] = j0 * bflo(v0.y) + j1 * bflo(v1.y) + j2 * bflo(v2.y) + j3 * bflo(v3.y);
      r[3] = j0 * bfhi(v0.y) + j1 * bfhi(v1.y) + j2 * bfhi(v2.y) + j3 * bfhi(v3.y);
      r[4] = j0 * bflo(v0.z) + j1 * bflo(v1.z) + j2 * bflo(v2.z) + j3 * bflo(v3.z);
      r[5] = j0 * bfhi(v0.z) + j1 * bfhi(v1.z) + j2 * bfhi(v2.z) + j3 * bfhi(v3.z);
      r[6] = j0 * bflo(v0.w) + j1 * bflo(v1.w) + j2 * bflo(v2.w) + j3 * bflo(v3.w);
      r[7] = j0 * bfhi(v0.w) + j1 * bfhi(v1.w) + j2 * bfhi(v2.w) + j3 * bfhi(v3.w);
      uint4 ov;
      asm("v_cvt_pk_bf16_f32 %0, %1, %2" : "=v"(ov.x) : "v"(r[0]), "v"(r[1]));
      asm("v_cvt_pk_bf16_f32 %0, %1, %2" : "=v"(ov.y) : "v"(r[2]), "v"(r[3]));
      asm("v_cvt_pk_bf16_f32 %0, %1, %2" : "=v"(ov.z) : "v"(r[4]), "v"(r[5]));
      asm("v_cvt_pk_bf16_f32 %0, %1, %2" : "=v"(ov.w) : "v"(r[6]), "v"(r[7]));
      *(uint4*)((char*)A + kcbA + src * 16) = ov;
    }
    if (wave < 4) {  // tap 8: one px-group per wave; geometry from LDS
      int src = (wave << 4) + q16;
      float j0 = gBw[src][0], j1 = gBw[src][1];
      float j2 = gBw[src][2], j3 = gBw[src][3];
      int c0 = gBa[src][0], c1 = gBa[src][1];
      int c2 = gBa[src][2], c3 = gBa[src][3];
      uint4 v0 = *(const uint4*)(xbt + c0 + co);
      uint4 v1 = *(const uint4*)(xbt + c1 + co);
      uint4 v2 = *(const uint4*)(xbt + c2 + co);
      uint4 v3 = *(const uint4*)(xbt + c3 + co);
      float r[8];
      r[0] = j0 * bflo(v0.x) + j1 * bflo(v1.x) + j2 * bflo(v2.x) + j3 * bflo(v3.x);
      r[1] = j0 * bfhi(v0.x) + j1 * bfhi(v1.x) + j2 * bfhi(v2.x) + j3 * bfhi(v3.x);
      r[2] = j0 * bflo(v0.y) + j1 * bflo(v1.y) + j2 * bflo(v2.y) + j3 * bflo(v3.y);
      r[3] = j0 * bfhi(v0.y) + j1 * bfhi(v1.y) + j2 * bfhi(v2.y) + j3 * bfhi(v3.y);
      r[4] = j0 * bflo(v0.z) + j1 * bflo(v1.z) + j2 * bflo(v2.z) + j3 * bflo(v3.z);
      r[5] = j0 * bfhi(v0.z) + j1 * bfhi(v1.z) + j2 * bfhi(v2.z) + j3 * bfhi(v3.z);
      r[6] = j0 * bflo(v0.w) + j1 * bflo(v1.w) + j2 * bflo(v2.w) + j3 * bflo(v3.w);
      r[7] = j0 * bfhi(v0.w) + j1 * bfhi(v1.w) + j2 * bfhi(v2.w) + j3 * bfhi(v3.w);
      uint4 ov;
      asm("v_cvt_pk_bf16_f32 %0, %1, %2" : "=v"(ov.x) : "v"(r[0]), "v"(r[1]));
      asm("v_cvt_pk_bf16_f32 %0, %1, %2" : "=v"(ov.y) : "v"(r[2]), "v"(r[3]));
      asm("v_cvt_pk_bf16_f32 %0, %1, %2" : "=v"(ov.z) : "v"(r[4]), "v"(r[5]));
      asm("v_cvt_pk_bf16_f32 %0, %1, %2" : "=v"(ov.w) : "v"(r[6]), "v"(r[7]));
      *(uint4*)((char*)A + kcb8 + src * 16) = ov;
    }
    __syncthreads();
    {
      int r0r = mh * 32 + (lane & 15);
      const bf16x8* wp = (const bf16x8*)wBf;
      __builtin_amdgcn_s_setprio(1);
#pragma unroll
      for (int tap = 0; tap < 9; ++tap) {
        bf16x8 bk = wp[((2 * tap + h) * 4 + n1) * 64 + lane];
        int kc = tap * 4 + kq;
        bf16x8 a0 = *(const bf16x8*)((const char*)A + (kc * 65 + r0r) * 16);
        bf16x8 a1 = *(const bf16x8*)((const char*)A + (kc * 65 + r0r + 16) * 16);
        acc0 = __builtin_amdgcn_mfma_f32_16x16x32_bf16(a0, bk, acc0, 0, 0, 0);
        acc1 = __builtin_amdgcn_mfma_f32_16x16x32_bf16(a1, bk, acc1, 0, 0, 0);
      }
      __builtin_amdgcn_s_setprio(0);
    }
    __syncthreads();
  }
  // residual (bf16 unpack) + A2 write
  {
    int c = n1 * 16 + (lane & 15);
    int pb = px0 + mh * 32 + ((lane >> 4) << 2);
#pragma unroll
    for (int r = 0; r < 4; r++) {
      acc0[r] += __uint_as_float((unsigned int)xtf[(size_t)(pb + r) * 64 + c] << 16);
      acc1[r] += __uint_as_float((unsigned int)xtf[(size_t)(pb + 16 + r) * 64 + c] << 16);
    }
    char* base = (char*)A + (c >> 3) * 1040 + (c & 7) * 2;
    int pxr = mh * 32 + ((lane >> 4) << 2);
#pragma unroll
    for (int r = 0; r < 4; r++) {
      *(unsigned short*)(base + (size_t)(pxr + r) * 16) = f2bf(acc0[r]);
      *(unsigned short*)(base + (size_t)(pxr + 16 + r) * 16) = f2bf(acc1[r]);
    }
  }
  __syncthreads();

  // ---- P6: GEMM2 (M=64, N=256, K=64), two n-half passes (16 acc regs each) ----
  unsigned short* tb = t3 + (size_t)bb * 256 * HW + px0;
  int mtq = (wave >> 2) * 32 + ((lane >> 4) << 2);
#pragma unroll
  for (int half = 0; half < 2; half++) {
    f32x4 cA[2], cB[2];
#pragma unroll
    for (int ni = 0; ni < 2; ni++) {
      cA[ni] = (f32x4){0.f, 0.f, 0.f, 0.f};
      cB[ni] = (f32x4){0.f, 0.f, 0.f, 0.f};
    }
    {
      int mt0 = (wave >> 2) * 2;
      const bf16x8* wp2 = (const bf16x8*)w3Bf;
      __builtin_amdgcn_s_setprio(1);
#pragma unroll
      for (int kt = 0; kt < 2; kt++) {
        int kc = kt * 4 + kq;
        bf16x8 aA = *(const bf16x8*)((const char*)A + (size_t)(kc * 65 + mt0 * 16 + (lane & 15)) * 16);
        bf16x8 aB = *(const bf16x8*)((const char*)A + (size_t)(kc * 65 + (mt0 + 1) * 16 + (lane & 15)) * 16);
#pragma unroll
        for (int ni = 0; ni < 2; ni++) {
          int ng = n1 * 4 + half * 2 + ni;
          bf16x8 bk = wp2[(kt * 16 + ng) * 64 + lane];
          cA[ni] = __builtin_amdgcn_mfma_f32_16x16x32_bf16(aA, bk, cA[ni], 0, 0, 0);
          cB[ni] = __builtin_amdgcn_mfma_f32_16x16x32_bf16(aB, bk, cB[ni], 0, 0, 0);
        }
      }
      __builtin_amdgcn_s_setprio(0);
    }
#pragma unroll
    for (int ni = 0; ni < 2; ni++) {
      int niA = half * 2 + ni;
      float s = 0.f, qq = 0.f;
#pragma unroll
      for (int r = 0; r < 4; r++) {
        float v0 = cA[ni][r], v1 = cB[ni][r];
        s += v0 + v1; qq += v0 * v0 + v1 * v1;
      }
      s += __shfl_down(s, 32); qq += __shfl_down(qq, 32);
      s += __shfl_down(s, 16); qq += __shfl_down(qq, 16);
      s += __shfl_down(s, 4);  qq += __shfl_down(qq, 4);
      s += __shfl_down(s, 2);  qq += __shfl_down(qq, 2);
      s += __shfl_down(s, 1);  qq += __shfl_down(qq, 1);
      if (lane == 0 || lane == 8) {
        int g = (n1 * 4 + niA) * 2 + (lane >> 3);
        int slot = ((bb * 32 + g) * 256 + tileid) * 2 + (wave >> 2);
        ps2[slot * 2] = s;
        ps2[slot * 2 + 1] = qq;
      }
      int o = (n1 * 4 + niA) * 16 + (lane & 15);
      unsigned short* p0 = tb + (size_t)o * HW + mtq;
      unsigned int u0, u1, u2, u3;
      asm("v_cvt_pk_bf16_f32 %0, %1, %2" : "=v"(u0) : "v"(cA[ni][0]), "v"(cA[ni][1]));
      asm("v_cvt_pk_bf16_f32 %0, %1, %2" : "=v"(u1) : "v"(cA[ni][2]), "v"(cA[ni][3]));
      asm("v_cvt_pk_bf16_f32 %0, %1, %2" : "=v"(u2) : "v"(cB[ni][0]), "v"(cB[ni][1]));
      asm("v_cvt_pk_bf16_f32 %0, %1, %2" : "=v"(u3) : "v"(cB[ni][2]), "v"(cB[ni][3]));
      *(uint2*)p0 = make_uint2(u0, u1);
      *(uint2*)(p0 + 16) = make_uint2(u2, u3);
    }
  }
}

// ---- K8: out = relu(gn2(t3_bf16)) + x ----
__global__ __launch_bounds__(256) void k_final(const unsigned short* __restrict__ t3, const float* __restrict__ x,
                                               const float* __restrict__ mrs, const float* __restrict__ g3,
                                               const float* __restrict__ b3, float* __restrict__ out) {
  int i4 = blockIdx.x * 256 + threadIdx.x;
  int b = i4 >> 20;
  int c = (i4 >> 12) & 255;
  int g = c >> 3;
  float mu = mrs[b * 32 + g], rs = mrs[128 + b * 32 + g];
  float ga = g3[c] * rs, be = b3[c] - mu * ga;
  uint2 tv = ((const uint2*)t3)[i4];
  float t0 = bflo(tv.x);
  float t1 = bfhi(tv.x);
  float t2 = bflo(tv.y);
  float t3v = bfhi(tv.y);
  float4 xv = ((const float4*)x)[i4];
  float4 r;
  r.x = fmaxf(t0 * ga + be, 0.f) + xv.x;
  r.y = fmaxf(t1 * ga + be, 0.f) + xv.y;
  r.z = fmaxf(t2 * ga + be, 0.f) + xv.z;
  r.w = fmaxf(t3v * ga + be, 0.f) + xv.w;
  ((float4*)out)[i4] = r;
}

extern "C" void kernel_launch(void* const* d_in, const int* in_sizes, int n_in,
                              void* d_out, int out_size, void* d_ws, size_t ws_size,
                              hipStream_t stream) {
  const float* x    = (const float*)d_in[0];
  const float* w1   = (const float*)d_in[1];
  const float* g1   = (const float*)d_in[2];
  const float* b1   = (const float*)d_in[3];
  const float* woff = (const float*)d_in[4];
  const float* wdef = (const float*)d_in[5];
  const float* w3   = (const float*)d_in[6];
  const float* g3   = (const float*)d_in[7];
  const float* b3   = (const float*)d_in[8];
  float* ws = (float*)d_ws;

  unsigned short* xdT = (unsigned short*)ws;               // 4,194,304 ush = 2,097,152 fl
  unsigned short* t3  = (unsigned short*)(ws + 2097152);   // 16,777,216 ush = 8,388,608 fl
  float* base = ws + 2097152 + 8388608;
  float* mrs1 = base;                     // 256
  float* mrs2 = mrs1 + 256;               // 256
  unsigned short* wA1f  = (unsigned short*)(mrs2 + 256);                        // 8,192 fl
  unsigned short* wBf   = (unsigned short*)(mrs2 + 256 + 8192);                 // 18,432 fl
  unsigned short* wofBf = (unsigned short*)(mrs2 + 256 + 8192 + 18432);         // 9,216 fl
  unsigned short* w3Bf  = (unsigned short*)(mrs2 + 256 + 8192 + 18432 + 9216);  // 16,384 fl
  float* ps   = mrs2 + 256 + 8192 + 18432 + 9216 + 16384;  // 65,536
  float* ps2  = ps + 65536;               // 131,072
  float* out  = (float*)d_out;

  hipLaunchKernelGGL(k_prep, dim3(144), dim3(256), 0, stream, w1, w3, wdef, woff, wA1f, wBf, wofBf, w3Bf);
  hipLaunchKernelGGL(k_conv1m, dim3(1024), dim3(256), 0, stream, x, wA1f, xdT, ps);
  hipLaunchKernelGGL(k_gnfin_p, dim3(128), dim3(256), 0, stream, ps, mrs1, 256, (float)(2 * HW));
  hipLaunchKernelGGL(k_gnapply_bf, dim3(2048), dim3(256), 0, stream, xdT, mrs1, g1, b1);
  hipLaunchKernelGGL(k_mega, dim3(1024), dim3(512), 0, stream, xdT, wofBf, wBf, w3Bf, t3, ps2);
  hipLaunchKernelGGL(k_gnfin_p, dim3(128), dim3(256), 0, stream, ps2, mrs2, 512, 131072.f);
  hipLaunchKernelGGL(k_final, dim3(16384), dim3(256), 0, stream, t3, x, mrs2, g3, b3, out);
}